// Round 4
// baseline (633.379 us; speedup 1.0000x reference)
//
#include <hip/hip_runtime.h>
#include <hip/hip_bf16.h>
#include <cstdint>
#include <cstddef>

using bf16 = __hip_bfloat16;

typedef __bf16 bf16x8_t __attribute__((ext_vector_type(8)));
typedef float  f32x4_t  __attribute__((ext_vector_type(4)));

static constexpr int Bb = 2;
static constexpr int Tt = 4096;
static constexpr int Gg = 4;
static constexpr int Cc = 1024;
static constexpr int Mm = Bb * Tt;   // 8192 rows (b*T+t)
static constexpr int GC = Gg * Cc;   // 4096

__device__ __forceinline__ float bfbits2f(unsigned u) {
  union { unsigned i; float f; } c; c.i = u << 16; return c.f;
}
__device__ __forceinline__ ushort f2bfbits(float v) {
  union { __hip_bfloat16 h; ushort u; } c; c.h = __float2bfloat16(v); return c.u;
}

__device__ __forceinline__ void store_val(bf16* p, float v)  { *p = __float2bfloat16(v); }
__device__ __forceinline__ void store_val(float* p, float v) { *p = v; }

// global -> LDS direct DMA, 16 B per lane. LDS dest must be the wave-uniform
// base (HW computes base + lane*16); global address is per-lane.
__device__ __forceinline__ void gld_lds16(const ushort* g, ushort* l) {
  __builtin_amdgcn_global_load_lds(
      (const __attribute__((address_space(1))) void*)g,
      (__attribute__((address_space(3))) void*)l, 16, 0, 0);
}

// ---------------------------------------------------------------------------
// fp32 -> bf16 (plain) and fp32 -> (hi, lo) split: hi = bf16(x),
// lo = bf16(x - hi). x-hi is exact in fp32 (Sterbenz), so hi+lo carries
// ~16 mantissa bits; bf16's fp32 exponent range means no subnormal hazards.
// ---------------------------------------------------------------------------
__global__ __launch_bounds__(256)
void cvt_bf16(const float* __restrict__ in, ushort* __restrict__ out, int n4)
{
  const int i = blockIdx.x * 256 + threadIdx.x;
  if (i >= n4) return;
  const float4 v = ((const float4*)in)[i];
  ushort4 o;
  o.x = f2bfbits(v.x); o.y = f2bfbits(v.y);
  o.z = f2bfbits(v.z); o.w = f2bfbits(v.w);
  ((ushort4*)out)[i] = o;
}

__global__ __launch_bounds__(256)
void cvt_split(const float* __restrict__ in, ushort* __restrict__ hi,
               ushort* __restrict__ lo, int n4)
{
  const int i = blockIdx.x * 256 + threadIdx.x;
  if (i >= n4) return;
  const float4 v = ((const float4*)in)[i];
  ushort4 h, l;
  h.x = f2bfbits(v.x); l.x = f2bfbits(v.x - bfbits2f(h.x));
  h.y = f2bfbits(v.y); l.y = f2bfbits(v.y - bfbits2f(h.y));
  h.z = f2bfbits(v.z); l.z = f2bfbits(v.z - bfbits2f(h.z));
  h.w = f2bfbits(v.w); l.w = f2bfbits(v.w - bfbits2f(h.w));
  ((ushort4*)hi)[i] = h;
  ((ushort4*)lo)[i] = l;
}

// ---------------------------------------------------------------------------
// GEMM1 (fused): split-bf16  k = embH@kwH^T + embH@kwL^T + embL@kwH^T + key_b,
// fp32 acc; 3 products fused in one K-loop (R3). R4 change: T3+T4 minimum
// 2-phase pipeline — double-buffered LDS (BK=32: 4 arrays x 8 KiB x 2 bufs
// = 64 KiB, keeps 2 blocks/CU) with COUNTED vmcnt + raw s_barrier, so the
// stage of tile kt+1 transfers under the 48 MFMAs of tile kt. __syncthreads
// would drain vmcnt(0) and kill the overlap (m99/m100); hence asm barriers
// with "memory" clobber.
// Swizzle (rule #21, both-sides-or-neither): LDS dest linear; global source
// column pre-XORed by f(r)=(r+(r>>2))&3 (chunk of 8 elems); ds_read XORs the
// same f. Enumerated: 16 lanes/quarter spread 2-per-bank-quad == optimal.
// A-frag A[m=lane&15][k=(lane>>4)*8+j]; C/D col=lane&15,row=(lane>>4)*4+reg.
// Epilogue (gate partials + atomicAdd) unchanged.
// ---------------------------------------------------------------------------
__global__ __launch_bounds__(256, 2)
void gemm_key_fused(const ushort* __restrict__ embH, const ushort* __restrict__ embL,
                    const ushort* __restrict__ kwH,  const ushort* __restrict__ kwL,
                    const float* __restrict__ key_b, const float* __restrict__ hid,
                    const float* __restrict__ wkn,   const float* __restrict__ wqn,
                    float* __restrict__ k2_part, float* __restrict__ dot_part,
                    float* __restrict__ q2_part)
{
  constexpr int K  = Cc;       // 1024
  constexpr int NT = K / 32;   // 32 K-steps
  // [2 bufs][128 rows][32 cols] per array, 8 KiB per buf per array
  __shared__ __align__(16) ushort sAH[2 * 4096];
  __shared__ __align__(16) ushort sAL[2 * 4096];
  __shared__ __align__(16) ushort sBH[2 * 4096];
  __shared__ __align__(16) ushort sBL[2 * 4096];

  const int tid  = threadIdx.x;
  const int lane = tid & 63;
  const int wave = tid >> 6;
  const int wm   = wave & 1;
  const int wn   = wave >> 1;
  const int row0 = blockIdx.y * 128;
  const int col0 = blockIdx.x * 128;

  // staging geometry: round p (0..1) covers rows p*64 + (tid>>2); chunk tid&3.
  // Dest is linear (wave-uniform base + lane*16B); source col pre-swizzled.
  const int sr0 = tid >> 2;                 // 0..63 (row within round)
  const int sch = tid & 3;                  // 16B chunk within row
  const int wofs = wave * 512;              // ushorts; + p*2048 per round

  // precompute per-thread global column offsets (swizzled) for both rounds
  int gcol[2]; int grA[2];
#pragma unroll
  for (int p = 0; p < 2; ++p) {
    const int r = p * 64 + sr0;
    gcol[p] = ((sch ^ ((r + (r >> 2)) & 3)) * 8);
    grA[p]  = r;
  }

  f32x4_t acc[4][4] = {};

  // stage K-step kt into buffer b (8 gld_lds per thread)
  auto stage = [&](int kt, int b) {
    const int kk = kt * 32;
#pragma unroll
    for (int p = 0; p < 2; ++p) {
      const size_t ao = (size_t)(row0 + grA[p]) * K + kk + gcol[p];
      const size_t bo = (size_t)(col0 + grA[p]) * K + kk + gcol[p];
      const int d = b * 4096 + p * 2048 + wofs;
      gld_lds16(embH + ao, sAH + d);
      gld_lds16(embL + ao, sAL + d);
      gld_lds16(kwH  + bo, sBH + d);
      gld_lds16(kwL  + bo, sBL + d);
    }
  };

  stage(0, 0);
  int cur = 0;

  for (int kt = 0; kt < NT; ++kt) {
    if (kt + 1 < NT) {
      stage(kt + 1, cur ^ 1);
      asm volatile("s_waitcnt vmcnt(8)" ::: "memory");   // stage(kt) done
    } else {
      asm volatile("s_waitcnt vmcnt(0)" ::: "memory");
    }
    asm volatile("s_barrier" ::: "memory");

    const ushort* bAH = sAH + cur * 4096;
    const ushort* bAL = sAL + cur * 4096;
    const ushort* bBH = sBH + cur * 4096;
    const ushort* bBL = sBL + cur * 4096;
    const int ch = lane >> 4;

    bf16x8_t afH[4], afL[4], bfH[4], bfL[4];
#pragma unroll
    for (int mi = 0; mi < 4; ++mi) {
      const int r  = wm * 64 + mi * 16 + (lane & 15);
      const int co = ((ch ^ ((r + (r >> 2)) & 3)) * 8);
      afH[mi] = *(const bf16x8_t*)(bAH + r * 32 + co);
      afL[mi] = *(const bf16x8_t*)(bAL + r * 32 + co);
    }
#pragma unroll
    for (int ni = 0; ni < 4; ++ni) {
      const int r  = wn * 64 + ni * 16 + (lane & 15);
      const int co = ((ch ^ ((r + (r >> 2)) & 3)) * 8);
      bfH[ni] = *(const bf16x8_t*)(bBH + r * 32 + co);
      bfL[ni] = *(const bf16x8_t*)(bBL + r * 32 + co);
    }
#pragma unroll
    for (int mi = 0; mi < 4; ++mi)
#pragma unroll
      for (int ni = 0; ni < 4; ++ni) {
        acc[mi][ni] = __builtin_amdgcn_mfma_f32_16x16x32_bf16(
            afH[mi], bfH[ni], acc[mi][ni], 0, 0, 0);
        acc[mi][ni] = __builtin_amdgcn_mfma_f32_16x16x32_bf16(
            afH[mi], bfL[ni], acc[mi][ni], 0, 0, 0);
        acc[mi][ni] = __builtin_amdgcn_mfma_f32_16x16x32_bf16(
            afL[mi], bfH[ni], acc[mi][ni], 0, 0, 0);
      }

    asm volatile("s_barrier" ::: "memory");   // protect buf overwrite next iter
    cur ^= 1;
  }

  // ---- fused gate-reduction epilogue ----
  const int lrow = lane >> 4;
  const int lcol = lane & 15;
  const int g    = col0 >> 10;   // 128-col block lies within one group

  float s2[4][4] = {};  // [mi][reg] sum_ni k^2
  float su[4][4] = {};  // [mi][reg] sum_ni k*wk*q*wq
  float sq[4][4] = {};  // [mi][reg] sum_ni q^2

#pragma unroll
  for (int ni = 0; ni < 4; ++ni) {
    const int col = col0 + wn * 64 + ni * 16 + lcol;
    const float kb = key_b[col];
    const float ww = wkn[col] * wqn[col];
#pragma unroll
    for (int mi = 0; mi < 4; ++mi) {
      const int rowb = row0 + wm * 64 + mi * 16 + lrow * 4;
#pragma unroll
      for (int r = 0; r < 4; ++r) {
        const float q = hid[(size_t)(rowb + r) * GC + col];
        const float k = acc[mi][ni][r] + kb;
        s2[mi][r] += k * k;
        su[mi][r] += k * ww * q;
        sq[mi][r] += q * q;
      }
    }
  }
  // reduce across the 16 lanes (lane&15) holding the same rows
#pragma unroll
  for (int off = 1; off < 16; off <<= 1) {
#pragma unroll
    for (int mi = 0; mi < 4; ++mi)
#pragma unroll
      for (int r = 0; r < 4; ++r) {
        s2[mi][r] += __shfl_xor(s2[mi][r], off);
        su[mi][r] += __shfl_xor(su[mi][r], off);
        sq[mi][r] += __shfl_xor(sq[mi][r], off);
      }
  }
  if (lcol == 0) {
#pragma unroll
    for (int mi = 0; mi < 4; ++mi) {
      const int rowb = row0 + wm * 64 + mi * 16 + lrow * 4;
#pragma unroll
      for (int r = 0; r < 4; ++r) {
        atomicAdd(&k2_part[(rowb + r) * Gg + g],  s2[mi][r]);
        atomicAdd(&dot_part[(rowb + r) * Gg + g], su[mi][r]);
        atomicAdd(&q2_part[(rowb + r) * Gg + g],  sq[mi][r]);
      }
    }
  }
}

// ---------------------------------------------------------------------------
// GEMM2: vproj = embH @ vwB^T + val_b  (plain bf16, fp32 out).
// R4: same 2-phase counted-vmcnt double-buffer (BK=64, 2 bufs x 32 KiB).
// Keeps the R2 st-8x64 swizzle (proven zero-conflict).
// ---------------------------------------------------------------------------
template <typename OutT>
__global__ __launch_bounds__(256, 2)
void gemm_bt(const ushort* __restrict__ A, const ushort* __restrict__ Bm,
             const float* __restrict__ bias, OutT* __restrict__ C,
             int M, int N, int K)
{
  __shared__ __align__(16) ushort sA[2 * 128 * 64];
  __shared__ __align__(16) ushort sB[2 * 128 * 64];

  const int tid  = threadIdx.x;
  const int lane = tid & 63;
  const int wave = tid >> 6;
  const int wm   = wave & 1;
  const int wn   = wave >> 1;
  const int row0 = blockIdx.y * 128;
  const int col0 = blockIdx.x * 128;

  const int srow = tid >> 3;
  const int scol = ((tid & 7) ^ (srow & 7)) * 8;
  const int wofs = wave * 512;

  f32x4_t acc[4][4] = {};

  const int NT = K / 64;

  auto stage = [&](int kt, int b) {
    const int kk = kt * 64;
#pragma unroll
    for (int p = 0; p < 4; ++p) {
      const int d = b * 8192 + p * 2048 + wofs;
      gld_lds16(A  + (size_t)(row0 + p * 32 + srow) * K + kk + scol, sA + d);
      gld_lds16(Bm + (size_t)(col0 + p * 32 + srow) * K + kk + scol, sB + d);
    }
  };

  stage(0, 0);
  int cur = 0;

  for (int kt = 0; kt < NT; ++kt) {
    if (kt + 1 < NT) {
      stage(kt + 1, cur ^ 1);
      asm volatile("s_waitcnt vmcnt(8)" ::: "memory");
    } else {
      asm volatile("s_waitcnt vmcnt(0)" ::: "memory");
    }
    asm volatile("s_barrier" ::: "memory");

    const ushort* bA = sA + cur * 8192;
    const ushort* bB = sB + cur * 8192;

#pragma unroll
    for (int ks = 0; ks < 2; ++ks) {
      const int cb = ks * 4 + (lane >> 4);
      const int ce = ((cb ^ (lane & 7)) * 8);
      bf16x8_t af[4], bfr[4];
#pragma unroll
      for (int mi = 0; mi < 4; ++mi) {
        const int r = wm * 64 + mi * 16 + (lane & 15);
        af[mi] = *(const bf16x8_t*)(bA + r * 64 + ce);
      }
#pragma unroll
      for (int ni = 0; ni < 4; ++ni) {
        const int r = wn * 64 + ni * 16 + (lane & 15);
        bfr[ni] = *(const bf16x8_t*)(bB + r * 64 + ce);
      }
#pragma unroll
      for (int mi = 0; mi < 4; ++mi)
#pragma unroll
        for (int ni = 0; ni < 4; ++ni)
          acc[mi][ni] = __builtin_amdgcn_mfma_f32_16x16x32_bf16(
              af[mi], bfr[ni], acc[mi][ni], 0, 0, 0);
    }

    asm volatile("s_barrier" ::: "memory");
    cur ^= 1;
  }

  const int lrow = lane >> 4;
  const int lcol = lane & 15;
#pragma unroll
  for (int ni = 0; ni < 4; ++ni) {
    const int col = col0 + wn * 64 + ni * 16 + lcol;
    const float bv = bias[col];
#pragma unroll
    for (int mi = 0; mi < 4; ++mi) {
      const int rowb = row0 + wm * 64 + mi * 16 + lrow * 4;
#pragma unroll
      for (int r = 0; r < 4; ++r)
        store_val(&C[(size_t)(rowb + r) * N + col], acc[mi][ni][r] + bv);
    }
  }
}

// ---------------------------------------------------------------------------
// Finalize: per (b,t) compute mean(vproj^2); combine with atomic partials to
// produce gate[b,t,g] and snorm[b,t,g] = gate/rms_v.
// ---------------------------------------------------------------------------
__global__ __launch_bounds__(256)
void finalize_kernel(const float* __restrict__ vproj,
                     const float* __restrict__ k2_part,
                     const float* __restrict__ dot_part,
                     const float* __restrict__ q2_part,
                     float* __restrict__ gate_o, float* __restrict__ snorm_o)
{
  const int bt   = blockIdx.x;
  const int tid  = threadIdx.x;
  const int g    = tid >> 6;
  const int lane = tid & 63;

  const float4 v4 = ((const float4*)(vproj + (size_t)bt * Cc))[tid];
  float pv = v4.x * v4.x + v4.y * v4.y + v4.z * v4.z + v4.w * v4.w;
#pragma unroll
  for (int off = 32; off > 0; off >>= 1) pv += __shfl_xor(pv, off);
  __shared__ float wsum[4];
  if (lane == 0) wsum[g] = pv;
  __syncthreads();

  if (lane == 0) {
    const float mv = (wsum[0] + wsum[1] + wsum[2] + wsum[3]) * (1.0f / 1024.0f);
    const float sk = k2_part[bt * Gg + g];
    const float sd = dot_part[bt * Gg + g];
    const float sq = q2_part[bt * Gg + g];
    const float rk = sqrtf(sk * (1.0f / 1024.0f) + 1e-5f);
    const float rq = sqrtf(sq * (1.0f / 1024.0f) + 1e-5f);
    const float graw = sd / (rk * rq) * (1.0f / 32.0f);   // sqrt(C)=32
    const float sgn = (graw >= 0.f) ? 1.f : -1.f;
    const float gate = 1.f / (1.f + expf(-sgn * sqrtf(fmaxf(fabsf(graw), 1e-6f))));
    const float rv = sqrtf(gate * gate * mv + 1e-5f);
    gate_o[bt * Gg + g]  = gate;
    snorm_o[bt * Gg + g] = gate / rv;
  }
}

// ---------------------------------------------------------------------------
// Conv: lags {0,3,6,9} share t mod 3 -> 3 phase subsequences, lag-1 K=4 conv.
// Thread = (b,g,c,phase,chunk); 3 running normed values; 3-step halo.
// ---------------------------------------------------------------------------
static constexpr int CJ  = 128;
static constexpr int NCH = 11;   // ceil(ceil(4096/3)/128)

__global__ __launch_bounds__(256)
void conv_kernel(const float* __restrict__ vproj, const float* __restrict__ gate,
                 const float* __restrict__ snorm, const float* __restrict__ wnm,
                 const float* __restrict__ cw, float* __restrict__ out)
{
  int x = blockIdx.x;
  const int cb = x & 3;  x >>= 2;
  const int p  = x % 3;  x /= 3;
  const int ch = x % NCH; x /= NCH;
  const int g  = x & 3;  x >>= 2;
  const int b  = x;
  const int c  = cb * 256 + threadIdx.x;

  const float wn = wnm[g * Cc + c];
  const float4 w = ((const float4*)cw)[g * Cc + c];

  int t = p + 3 * (ch * CJ);
  if (t >= Tt) return;

  float n1 = 0.f, n2 = 0.f, n3 = 0.f;
#pragma unroll
  for (int h = 3; h >= 1; --h) {
    const int th = t - 3 * h;
    float nv = 0.f;
    if (th >= 0) {
      const int bt = b * Tt + th;
      nv = vproj[(size_t)bt * Cc + c] * snorm[bt * Gg + g] * wn;
    }
    n3 = n2; n2 = n1; n1 = nv;
  }

  for (int j = 0; j < CJ && t < Tt; ++j, t += 3) {
    const int bt = b * Tt + t;
    const float vp  = vproj[(size_t)bt * Cc + c];
    const float gt  = gate[bt * Gg + g];
    const float sn  = snorm[bt * Gg + g];
    const float cur = vp * sn * wn;
    const float a   = w.x * n3 + w.y * n2 + w.z * n1 + w.w * cur;
    const float si  = a / (1.f + __expf(-a));
    out[((size_t)bt * Gg + g) * Cc + c] = vp * gt + si;
    n3 = n2; n2 = n1; n1 = cur;
  }
}

// ---------------------------------------------------------------------------
extern "C" void kernel_launch(void* const* d_in, const int* in_sizes, int n_in,
                              void* d_out, int out_size, void* d_ws, size_t ws_size,
                              hipStream_t stream)
{
  const float* emb   = (const float*)d_in[0];
  const float* hid   = (const float*)d_in[1];
  const float* key_w = (const float*)d_in[2];
  const float* key_b = (const float*)d_in[3];
  const float* val_w = (const float*)d_in[4];
  const float* val_b = (const float*)d_in[5];
  const float* wkn   = (const float*)d_in[6];
  const float* wqn   = (const float*)d_in[7];
  const float* wnm   = (const float*)d_in[8];
  const float* cwt   = (const float*)d_in[9];
  float* out = (float*)d_out;

  // ws: embH 16.8M | embL 16.8M | kwH 8.4M | kwL 8.4M | vwB 2.1M |
  //     vproj 33.5M | k2/dot/q2/gate/snorm 5x128K   (~86.6 MB)
  char* ws = (char*)d_ws;
  ushort* embH  = (ushort*)ws;  ws += (size_t)Mm * Cc * 2;
  ushort* embL  = (ushort*)ws;  ws += (size_t)Mm * Cc * 2;
  ushort* kwH   = (ushort*)ws;  ws += (size_t)GC * Cc * 2;
  ushort* kwL   = (ushort*)ws;  ws += (size_t)GC * Cc * 2;
  ushort* vwB   = (ushort*)ws;  ws += (size_t)Cc * Cc * 2;
  float*  vproj = (float*)ws;   ws += (size_t)Mm * Cc * 4;
  float*  k2p   = (float*)ws;   ws += (size_t)Mm * Gg * 4;
  float*  dotp  = (float*)ws;   ws += (size_t)Mm * Gg * 4;
  float*  q2p   = (float*)ws;   ws += (size_t)Mm * Gg * 4;
  float*  gate  = (float*)ws;   ws += (size_t)Mm * Gg * 4;
  float*  snorm = (float*)ws;

  // zero the atomic partials (contiguous k2p|dotp|q2p)
  hipMemsetAsync(k2p, 0, (size_t)3 * Mm * Gg * 4, stream);

  dim3 blk(256);
  cvt_split<<<dim3((Mm * Cc / 4) / 256), blk, 0, stream>>>(emb,   embH, embL, Mm * Cc / 4);
  cvt_split<<<dim3((GC * Cc / 4) / 256), blk, 0, stream>>>(key_w, kwH,  kwL,  GC * Cc / 4);
  cvt_bf16 <<<dim3((Cc * Cc / 4) / 256), blk, 0, stream>>>(val_w, vwB,  Cc * Cc / 4);

  gemm_key_fused<<<dim3(GC / 128, Mm / 128), blk, 0, stream>>>(
      embH, embL, kwH, kwL, key_b, hid, wkn, wqn, k2p, dotp, q2p);

  gemm_bt<float><<<dim3(Cc / 128, Mm / 128), blk, 0, stream>>>(
      embH, vwB, val_b, vproj, Mm, Cc, Cc);

  finalize_kernel<<<dim3(Mm), blk, 0, stream>>>(vproj, k2p, dotp, q2p, gate, snorm);

  const int nblocks = Bb * Gg * NCH * 3 * (Cc / 256);  // 1056
  conv_kernel<<<dim3(nblocks), blk, 0, stream>>>(vproj, gate, snorm, wnm, cwt, out);
}

// Round 5
// 615.527 us; speedup vs baseline: 1.0290x; 1.0290x over previous
//
#include <hip/hip_runtime.h>
#include <hip/hip_bf16.h>
#include <cstdint>
#include <cstddef>

using bf16 = __hip_bfloat16;

typedef __bf16 bf16x8_t __attribute__((ext_vector_type(8)));
typedef float  f32x4_t  __attribute__((ext_vector_type(4)));

static constexpr int Bb = 2;
static constexpr int Tt = 4096;
static constexpr int Gg = 4;
static constexpr int Cc = 1024;
static constexpr int Mm = Bb * Tt;   // 8192 rows (b*T+t)
static constexpr int GC = Gg * Cc;   // 4096

__device__ __forceinline__ float bfbits2f(unsigned u) {
  union { unsigned i; float f; } c; c.i = u << 16; return c.f;
}
__device__ __forceinline__ ushort f2bfbits(float v) {
  union { __hip_bfloat16 h; ushort u; } c; c.h = __float2bfloat16(v); return c.u;
}

__device__ __forceinline__ void store_val(bf16* p, float v)  { *p = __float2bfloat16(v); }
__device__ __forceinline__ void store_val(float* p, float v) { *p = v; }

// global -> LDS direct DMA, 16 B per lane. LDS dest must be the wave-uniform
// base (HW computes base + lane*16); global address is per-lane.
__device__ __forceinline__ void gld_lds16(const ushort* g, ushort* l) {
  __builtin_amdgcn_global_load_lds(
      (const __attribute__((address_space(1))) void*)g,
      (__attribute__((address_space(3))) void*)l, 16, 0, 0);
}

// ---------------------------------------------------------------------------
// fp32 -> bf16 (plain) and fp32 -> (hi, lo) split: hi = bf16(x),
// lo = bf16(x - hi). x-hi is exact in fp32 (Sterbenz), so hi+lo carries
// ~16 mantissa bits; bf16's fp32 exponent range means no subnormal hazards.
// ---------------------------------------------------------------------------
__global__ __launch_bounds__(256)
void cvt_bf16(const float* __restrict__ in, ushort* __restrict__ out, int n4)
{
  const int i = blockIdx.x * 256 + threadIdx.x;
  if (i >= n4) return;
  const float4 v = ((const float4*)in)[i];
  ushort4 o;
  o.x = f2bfbits(v.x); o.y = f2bfbits(v.y);
  o.z = f2bfbits(v.z); o.w = f2bfbits(v.w);
  ((ushort4*)out)[i] = o;
}

__global__ __launch_bounds__(256)
void cvt_split(const float* __restrict__ in, ushort* __restrict__ hi,
               ushort* __restrict__ lo, int n4)
{
  const int i = blockIdx.x * 256 + threadIdx.x;
  if (i >= n4) return;
  const float4 v = ((const float4*)in)[i];
  ushort4 h, l;
  h.x = f2bfbits(v.x); l.x = f2bfbits(v.x - bfbits2f(h.x));
  h.y = f2bfbits(v.y); l.y = f2bfbits(v.y - bfbits2f(h.y));
  h.z = f2bfbits(v.z); l.z = f2bfbits(v.z - bfbits2f(h.z));
  h.w = f2bfbits(v.w); l.w = f2bfbits(v.w - bfbits2f(h.w));
  ((ushort4*)hi)[i] = h;
  ((ushort4*)lo)[i] = l;
}

// ---------------------------------------------------------------------------
// GEMM1 (fused): split-bf16  k = embH@kwH^T + embH@kwL^T + embL@kwH^T + key_b,
// fp32 acc; 3 products fused in one K-loop.
// R5 change: restore the m97 resource profile (32 KiB LDS, 2-barrier loop,
// multi-block residency) while keeping the fusion, via H|L CONCATENATION:
// per K-step of 32, sA[128][64] holds [AH(32 elems) | AL(32 elems)] per row
// (sB likewise) -- byte-identical geometry to the R2-proven zero-conflict
// layout (128-B rows, 8 chunks of 8 elems, chunk ^ (row&7) involution; the
// XOR freely permutes chunks across the H/L halves, consistently on the
// stage and read sides per rule #21). Single-buffered, plain __syncthreads
// (R4's 2-phase counted-vmcnt was null, per the T3/T4 regime gate), and
// __launch_bounds__(256,4) so 3-4 blocks/CU co-schedule (m114 overlap --
// the mechanism behind m97's 874 TF). R4's conflicting BK=32 swizzle is gone.
// A-frag A[m=lane&15][k=(lane>>4)*8+j]; C/D col=lane&15,row=(lane>>4)*4+reg.
// Epilogue (gate partials + atomicAdd) unchanged.
// ---------------------------------------------------------------------------
__global__ __launch_bounds__(256, 4)
void gemm_key_fused(const ushort* __restrict__ embH, const ushort* __restrict__ embL,
                    const ushort* __restrict__ kwH,  const ushort* __restrict__ kwL,
                    const float* __restrict__ key_b, const float* __restrict__ hid,
                    const float* __restrict__ wkn,   const float* __restrict__ wqn,
                    float* __restrict__ k2_part, float* __restrict__ dot_part,
                    float* __restrict__ q2_part)
{
  constexpr int K = Cc;  // 1024
  __shared__ __align__(16) ushort sA[128 * 64];   // [row][ AH(32) | AL(32) ] swizzled
  __shared__ __align__(16) ushort sB[128 * 64];   // [row][ BH(32) | BL(32) ] swizzled

  const int tid  = threadIdx.x;
  const int lane = tid & 63;
  const int wave = tid >> 6;
  const int wm   = wave & 1;
  const int wn   = wave >> 1;
  const int row0 = blockIdx.y * 128;
  const int col0 = blockIdx.x * 128;

  // Staging: round p covers rows p*32 + (tid>>3); LDS chunk tid&7 at that row
  // receives SOURCE chunk (tid&7)^(row&7). Source chunks 0-3 = H half,
  // 4-7 = L half; within-half elem offset (chunk&3)*8. The H/L select and
  // elem offset are per-thread constants (32 % 8 == 0 keeps row&7 fixed
  // across rounds), so no divergence in the loop.
  const int srow = tid >> 3;                       // 0..31
  const int schk = (tid & 7) ^ (srow & 7);         // source chunk 0..7
  const ushort* aBase = (schk < 4) ? embH : embL;
  const ushort* bBase = (schk < 4) ? kwH  : kwL;
  const int selem = (schk & 3) * 8;                // elem offset in K-step
  const int wofs  = wave * 512;                    // + p*2048 per round

  f32x4_t acc[4][4] = {};

  for (int kt = 0; kt < K; kt += 32) {
#pragma unroll
    for (int p = 0; p < 4; ++p) {
      gld_lds16(aBase + (size_t)(row0 + p * 32 + srow) * K + kt + selem,
                sA + p * 2048 + wofs);
      gld_lds16(bBase + (size_t)(col0 + p * 32 + srow) * K + kt + selem,
                sB + p * 2048 + wofs);
    }
    __syncthreads();

    // frag reads: k-group kgrp = lane>>4 (8 elems each, BK=32).
    // src chunk for H = kgrp, for L = kgrp+4; LDS chunk = src ^ (r&7),
    // and r&7 == lane&7 here (row bases are multiples of 8).
    const int cH = (lane >> 4) ^ (lane & 7);   // LDS chunk for H half
    const int cL = cH ^ 4;                     // LDS chunk for L half

    bf16x8_t afH[4], afL[4], bfH[4], bfL[4];
#pragma unroll
    for (int mi = 0; mi < 4; ++mi) {
      const int r = wm * 64 + mi * 16 + (lane & 15);
      afH[mi] = *(const bf16x8_t*)(sA + r * 64 + cH * 8);
      afL[mi] = *(const bf16x8_t*)(sA + r * 64 + cL * 8);
    }
#pragma unroll
    for (int ni = 0; ni < 4; ++ni) {
      const int r = wn * 64 + ni * 16 + (lane & 15);
      bfH[ni] = *(const bf16x8_t*)(sB + r * 64 + cH * 8);
      bfL[ni] = *(const bf16x8_t*)(sB + r * 64 + cL * 8);
    }
#pragma unroll
    for (int mi = 0; mi < 4; ++mi)
#pragma unroll
      for (int ni = 0; ni < 4; ++ni) {
        acc[mi][ni] = __builtin_amdgcn_mfma_f32_16x16x32_bf16(
            afH[mi], bfH[ni], acc[mi][ni], 0, 0, 0);
        acc[mi][ni] = __builtin_amdgcn_mfma_f32_16x16x32_bf16(
            afH[mi], bfL[ni], acc[mi][ni], 0, 0, 0);
        acc[mi][ni] = __builtin_amdgcn_mfma_f32_16x16x32_bf16(
            afL[mi], bfH[ni], acc[mi][ni], 0, 0, 0);
      }
    __syncthreads();
  }

  // ---- fused gate-reduction epilogue ----
  const int lrow = lane >> 4;
  const int lcol = lane & 15;
  const int g    = col0 >> 10;   // 128-col block lies within one group

  float s2[4][4] = {};  // [mi][reg] sum_ni k^2
  float su[4][4] = {};  // [mi][reg] sum_ni k*wk*q*wq
  float sq[4][4] = {};  // [mi][reg] sum_ni q^2

#pragma unroll
  for (int ni = 0; ni < 4; ++ni) {
    const int col = col0 + wn * 64 + ni * 16 + lcol;
    const float kb = key_b[col];
    const float ww = wkn[col] * wqn[col];
#pragma unroll
    for (int mi = 0; mi < 4; ++mi) {
      const int rowb = row0 + wm * 64 + mi * 16 + lrow * 4;
#pragma unroll
      for (int r = 0; r < 4; ++r) {
        const float q = hid[(size_t)(rowb + r) * GC + col];
        const float k = acc[mi][ni][r] + kb;
        s2[mi][r] += k * k;
        su[mi][r] += k * ww * q;
        sq[mi][r] += q * q;
      }
    }
  }
  // reduce across the 16 lanes (lane&15) holding the same rows
#pragma unroll
  for (int off = 1; off < 16; off <<= 1) {
#pragma unroll
    for (int mi = 0; mi < 4; ++mi)
#pragma unroll
      for (int r = 0; r < 4; ++r) {
        s2[mi][r] += __shfl_xor(s2[mi][r], off);
        su[mi][r] += __shfl_xor(su[mi][r], off);
        sq[mi][r] += __shfl_xor(sq[mi][r], off);
      }
  }
  if (lcol == 0) {
#pragma unroll
    for (int mi = 0; mi < 4; ++mi) {
      const int rowb = row0 + wm * 64 + mi * 16 + lrow * 4;
#pragma unroll
      for (int r = 0; r < 4; ++r) {
        atomicAdd(&k2_part[(rowb + r) * Gg + g],  s2[mi][r]);
        atomicAdd(&dot_part[(rowb + r) * Gg + g], su[mi][r]);
        atomicAdd(&q2_part[(rowb + r) * Gg + g],  sq[mi][r]);
      }
    }
  }
}

// ---------------------------------------------------------------------------
// GEMM2: vproj = embH @ vwB^T + val_b  (plain bf16, fp32 out).
// R5: reverted to the R2 proven structure (single 32 KiB buffer, syncthreads,
// st-8x64 swizzle) with __launch_bounds__(256,4) for multi-block residency.
// ---------------------------------------------------------------------------
template <typename OutT>
__global__ __launch_bounds__(256, 4)
void gemm_bt(const ushort* __restrict__ A, const ushort* __restrict__ Bm,
             const float* __restrict__ bias, OutT* __restrict__ C,
             int M, int N, int K)
{
  __shared__ __align__(16) ushort sA[128 * 64];
  __shared__ __align__(16) ushort sB[128 * 64];

  const int tid  = threadIdx.x;
  const int lane = tid & 63;
  const int wave = tid >> 6;
  const int wm   = wave & 1;
  const int wn   = wave >> 1;
  const int row0 = blockIdx.y * 128;
  const int col0 = blockIdx.x * 128;

  const int srow = tid >> 3;
  const int scol = ((tid & 7) ^ (srow & 7)) * 8;
  ushort* aWB = sA + wave * 512;
  ushort* bWB = sB + wave * 512;

  f32x4_t acc[4][4] = {};

  for (int kt = 0; kt < K; kt += 64) {
#pragma unroll
    for (int p = 0; p < 4; ++p) {
      gld_lds16(A  + (size_t)(row0 + p * 32 + srow) * K + kt + scol,
                aWB + p * 2048);
      gld_lds16(Bm + (size_t)(col0 + p * 32 + srow) * K + kt + scol,
                bWB + p * 2048);
    }
    __syncthreads();

#pragma unroll
    for (int ks = 0; ks < 2; ++ks) {
      const int cb = ks * 4 + (lane >> 4);
      const int ce = ((cb ^ (lane & 7)) * 8);
      bf16x8_t af[4], bfr[4];
#pragma unroll
      for (int mi = 0; mi < 4; ++mi) {
        const int r = wm * 64 + mi * 16 + (lane & 15);
        af[mi] = *(const bf16x8_t*)(sA + r * 64 + ce);
      }
#pragma unroll
      for (int ni = 0; ni < 4; ++ni) {
        const int r = wn * 64 + ni * 16 + (lane & 15);
        bfr[ni] = *(const bf16x8_t*)(sB + r * 64 + ce);
      }
#pragma unroll
      for (int mi = 0; mi < 4; ++mi)
#pragma unroll
        for (int ni = 0; ni < 4; ++ni)
          acc[mi][ni] = __builtin_amdgcn_mfma_f32_16x16x32_bf16(
              af[mi], bfr[ni], acc[mi][ni], 0, 0, 0);
    }
    __syncthreads();
  }

  const int lrow = lane >> 4;
  const int lcol = lane & 15;
#pragma unroll
  for (int ni = 0; ni < 4; ++ni) {
    const int col = col0 + wn * 64 + ni * 16 + lcol;
    const float bv = bias[col];
#pragma unroll
    for (int mi = 0; mi < 4; ++mi) {
      const int rowb = row0 + wm * 64 + mi * 16 + lrow * 4;
#pragma unroll
      for (int r = 0; r < 4; ++r)
        store_val(&C[(size_t)(rowb + r) * N + col], acc[mi][ni][r] + bv);
    }
  }
}

// ---------------------------------------------------------------------------
// Finalize: per (b,t) compute mean(vproj^2); combine with atomic partials to
// produce gate[b,t,g] and snorm[b,t,g] = gate/rms_v.
// ---------------------------------------------------------------------------
__global__ __launch_bounds__(256)
void finalize_kernel(const float* __restrict__ vproj,
                     const float* __restrict__ k2_part,
                     const float* __restrict__ dot_part,
                     const float* __restrict__ q2_part,
                     float* __restrict__ gate_o, float* __restrict__ snorm_o)
{
  const int bt   = blockIdx.x;
  const int tid  = threadIdx.x;
  const int g    = tid >> 6;
  const int lane = tid & 63;

  const float4 v4 = ((const float4*)(vproj + (size_t)bt * Cc))[tid];
  float pv = v4.x * v4.x + v4.y * v4.y + v4.z * v4.z + v4.w * v4.w;
#pragma unroll
  for (int off = 32; off > 0; off >>= 1) pv += __shfl_xor(pv, off);
  __shared__ float wsum[4];
  if (lane == 0) wsum[g] = pv;
  __syncthreads();

  if (lane == 0) {
    const float mv = (wsum[0] + wsum[1] + wsum[2] + wsum[3]) * (1.0f / 1024.0f);
    const float sk = k2_part[bt * Gg + g];
    const float sd = dot_part[bt * Gg + g];
    const float sq = q2_part[bt * Gg + g];
    const float rk = sqrtf(sk * (1.0f / 1024.0f) + 1e-5f);
    const float rq = sqrtf(sq * (1.0f / 1024.0f) + 1e-5f);
    const float graw = sd / (rk * rq) * (1.0f / 32.0f);   // sqrt(C)=32
    const float sgn = (graw >= 0.f) ? 1.f : -1.f;
    const float gate = 1.f / (1.f + expf(-sgn * sqrtf(fmaxf(fabsf(graw), 1e-6f))));
    const float rv = sqrtf(gate * gate * mv + 1e-5f);
    gate_o[bt * Gg + g]  = gate;
    snorm_o[bt * Gg + g] = gate / rv;
  }
}

// ---------------------------------------------------------------------------
// Conv: lags {0,3,6,9} share t mod 3 -> 3 phase subsequences, lag-1 K=4 conv.
// Thread = (b,g,c,phase,chunk); 3 running normed values; 3-step halo.
// ---------------------------------------------------------------------------
static constexpr int CJ  = 128;
static constexpr int NCH = 11;   // ceil(ceil(4096/3)/128)

__global__ __launch_bounds__(256)
void conv_kernel(const float* __restrict__ vproj, const float* __restrict__ gate,
                 const float* __restrict__ snorm, const float* __restrict__ wnm,
                 const float* __restrict__ cw, float* __restrict__ out)
{
  int x = blockIdx.x;
  const int cb = x & 3;  x >>= 2;
  const int p  = x % 3;  x /= 3;
  const int ch = x % NCH; x /= NCH;
  const int g  = x & 3;  x >>= 2;
  const int b  = x;
  const int c  = cb * 256 + threadIdx.x;

  const float wn = wnm[g * Cc + c];
  const float4 w = ((const float4*)cw)[g * Cc + c];

  int t = p + 3 * (ch * CJ);
  if (t >= Tt) return;

  float n1 = 0.f, n2 = 0.f, n3 = 0.f;
#pragma unroll
  for (int h = 3; h >= 1; --h) {
    const int th = t - 3 * h;
    float nv = 0.f;
    if (th >= 0) {
      const int bt = b * Tt + th;
      nv = vproj[(size_t)bt * Cc + c] * snorm[bt * Gg + g] * wn;
    }
    n3 = n2; n2 = n1; n1 = nv;
  }

  for (int j = 0; j < CJ && t < Tt; ++j, t += 3) {
    const int bt = b * Tt + t;
    const float vp  = vproj[(size_t)bt * Cc + c];
    const float gt  = gate[bt * Gg + g];
    const float sn  = snorm[bt * Gg + g];
    const float cur = vp * sn * wn;
    const float a   = w.x * n3 + w.y * n2 + w.z * n1 + w.w * cur;
    const float si  = a / (1.f + __expf(-a));
    out[((size_t)bt * Gg + g) * Cc + c] = vp * gt + si;
    n3 = n2; n2 = n1; n1 = cur;
  }
}

// ---------------------------------------------------------------------------
extern "C" void kernel_launch(void* const* d_in, const int* in_sizes, int n_in,
                              void* d_out, int out_size, void* d_ws, size_t ws_size,
                              hipStream_t stream)
{
  const float* emb   = (const float*)d_in[0];
  const float* hid   = (const float*)d_in[1];
  const float* key_w = (const float*)d_in[2];
  const float* key_b = (const float*)d_in[3];
  const float* val_w = (const float*)d_in[4];
  const float* val_b = (const float*)d_in[5];
  const float* wkn   = (const float*)d_in[6];
  const float* wqn   = (const float*)d_in[7];
  const float* wnm   = (const float*)d_in[8];
  const float* cwt   = (const float*)d_in[9];
  float* out = (float*)d_out;

  // ws: embH 16.8M | embL 16.8M | kwH 8.4M | kwL 8.4M | vwB 2.1M |
  //     vproj 33.5M | k2/dot/q2/gate/snorm 5x128K   (~86.6 MB)
  char* ws = (char*)d_ws;
  ushort* embH  = (ushort*)ws;  ws += (size_t)Mm * Cc * 2;
  ushort* embL  = (ushort*)ws;  ws += (size_t)Mm * Cc * 2;
  ushort* kwH   = (ushort*)ws;  ws += (size_t)GC * Cc * 2;
  ushort* kwL   = (ushort*)ws;  ws += (size_t)GC * Cc * 2;
  ushort* vwB   = (ushort*)ws;  ws += (size_t)Cc * Cc * 2;
  float*  vproj = (float*)ws;   ws += (size_t)Mm * Cc * 4;
  float*  k2p   = (float*)ws;   ws += (size_t)Mm * Gg * 4;
  float*  dotp  = (float*)ws;   ws += (size_t)Mm * Gg * 4;
  float*  q2p   = (float*)ws;   ws += (size_t)Mm * Gg * 4;
  float*  gate  = (float*)ws;   ws += (size_t)Mm * Gg * 4;
  float*  snorm = (float*)ws;

  // zero the atomic partials (contiguous k2p|dotp|q2p)
  hipMemsetAsync(k2p, 0, (size_t)3 * Mm * Gg * 4, stream);

  dim3 blk(256);
  cvt_split<<<dim3((Mm * Cc / 4) / 256), blk, 0, stream>>>(emb,   embH, embL, Mm * Cc / 4);
  cvt_split<<<dim3((GC * Cc / 4) / 256), blk, 0, stream>>>(key_w, kwH,  kwL,  GC * Cc / 4);
  cvt_bf16 <<<dim3((Cc * Cc / 4) / 256), blk, 0, stream>>>(val_w, vwB,  Cc * Cc / 4);

  gemm_key_fused<<<dim3(GC / 128, Mm / 128), blk, 0, stream>>>(
      embH, embL, kwH, kwL, key_b, hid, wkn, wqn, k2p, dotp, q2p);

  gemm_bt<float><<<dim3(Cc / 128, Mm / 128), blk, 0, stream>>>(
      embH, vwB, val_b, vproj, Mm, Cc, Cc);

  finalize_kernel<<<dim3(Mm), blk, 0, stream>>>(vproj, k2p, dotp, q2p, gate, snorm);

  const int nblocks = Bb * Gg * NCH * 3 * (Cc / 256);  // 1056
  conv_kernel<<<dim3(nblocks), blk, 0, stream>>>(vproj, gate, snorm, wnm, cwt, out);
}

// Round 6
// 588.663 us; speedup vs baseline: 1.0760x; 1.0456x over previous
//
#include <hip/hip_runtime.h>
#include <hip/hip_bf16.h>
#include <cstdint>
#include <cstddef>

using bf16 = __hip_bfloat16;

typedef __bf16 bf16x8_t __attribute__((ext_vector_type(8)));
typedef float  f32x4_t  __attribute__((ext_vector_type(4)));

static constexpr int Bb = 2;
static constexpr int Tt = 4096;
static constexpr int Gg = 4;
static constexpr int Cc = 1024;
static constexpr int Mm = Bb * Tt;   // 8192 rows (b*T+t)
static constexpr int GC = Gg * Cc;   // 4096

__device__ __forceinline__ float bfbits2f(unsigned u) {
  union { unsigned i; float f; } c; c.i = u << 16; return c.f;
}
__device__ __forceinline__ ushort f2bfbits(float v) {
  union { __hip_bfloat16 h; ushort u; } c; c.h = __float2bfloat16(v); return c.u;
}

__device__ __forceinline__ void store_val(bf16* p, float v)  { *p = __float2bfloat16(v); }
__device__ __forceinline__ void store_val(float* p, float v) { *p = v; }

// global -> LDS direct DMA, 16 B per lane. LDS dest must be the wave-uniform
// base (HW computes base + lane*16); global address is per-lane.
__device__ __forceinline__ void gld_lds16(const ushort* g, ushort* l) {
  __builtin_amdgcn_global_load_lds(
      (const __attribute__((address_space(1))) void*)g,
      (__attribute__((address_space(3))) void*)l, 16, 0, 0);
}

// ---------------------------------------------------------------------------
// fp32 -> bf16 (plain) and fp32 -> (hi, lo) split: hi = bf16(x),
// lo = bf16(x - hi). x-hi is exact in fp32 (Sterbenz), so hi+lo carries
// ~16 mantissa bits; bf16's fp32 exponent range means no subnormal hazards.
// ---------------------------------------------------------------------------
__global__ __launch_bounds__(256)
void cvt_bf16(const float* __restrict__ in, ushort* __restrict__ out, int n4)
{
  const int i = blockIdx.x * 256 + threadIdx.x;
  if (i >= n4) return;
  const float4 v = ((const float4*)in)[i];
  ushort4 o;
  o.x = f2bfbits(v.x); o.y = f2bfbits(v.y);
  o.z = f2bfbits(v.z); o.w = f2bfbits(v.w);
  ((ushort4*)out)[i] = o;
}

__global__ __launch_bounds__(256)
void cvt_split(const float* __restrict__ in, ushort* __restrict__ hi,
               ushort* __restrict__ lo, int n4)
{
  const int i = blockIdx.x * 256 + threadIdx.x;
  if (i >= n4) return;
  const float4 v = ((const float4*)in)[i];
  ushort4 h, l;
  h.x = f2bfbits(v.x); l.x = f2bfbits(v.x - bfbits2f(h.x));
  h.y = f2bfbits(v.y); l.y = f2bfbits(v.y - bfbits2f(h.y));
  h.z = f2bfbits(v.z); l.z = f2bfbits(v.z - bfbits2f(h.z));
  h.w = f2bfbits(v.w); l.w = f2bfbits(v.w - bfbits2f(h.w));
  ((ushort4*)hi)[i] = h;
  ((ushort4*)lo)[i] = l;
}

// ---------------------------------------------------------------------------
// GEMM1 (fused): split-bf16  k = embH@kwH^T + embH@kwL^T + embL@kwH^T + key_b,
// fp32 acc; 3 products fused per K-tile (R3).
// R6: 8-phase 256^2 schedule (m201 quadrant) -- the documented regime where
// counted-vmcnt pipelining pays (2-phase ceiling ~650 TF, hit in R3/R4/R5).
// Geometry: BM=BN=256, concat-BK=64 (32 real K x [H|L]), 512 thr / 8 waves
// (wm in {0,1} x wn in {0..3}); per-wave out 128x64 as 4 quadrants
// (qm,qn): rows qm*128+wm*64+[0,64), cols qn*128+wn*32+[0,32).
// LDS 128 KiB: 2 dbuf x (A 32K + B 32K). Tile u -> buf u&1.
// Stage pairs per tile (2 x gld_lds16 each, 64-row rounds of 8 KB):
// [Ah0 rows 0-127 | Bh0 0-127 | Bh1 128-255 | Ah1 128-255], issued one pair
// per phase for tile u+1. Phase needs: P1(0,0):Ah0+Bh0, P2(0,1):Ah0+Bh1,
// P3(1,0):Ah1+Bh0, P4(1,1):Ah1+Bh1.
// vmcnt FIFO proof (retire = issue order): at u.P4-end outstanding =
// u+1's 8 -> vmcnt(4) retires Ah0,Bh0 (P1 ready). u.P1-end: outstanding =
// u's [Bh1,Ah1](4) + u+1's Ah0(2) -> vmcnt(4) retires u.Bh1 (P2 ready).
// u.P2-end: u.Ah1(2) + u+1's 4 -> vmcnt(4) retires u.Ah1 (P3 ready).
// P3-end: nothing new needed. Never vmcnt(0) in the loop.
// Buffer safety: u+1 loads -> buf^1 whose readers (tile u-1) finished with
// lgkmcnt(0) before u-1.P4's trailing barrier.
// T2 swizzle: byte-identical to R5's zero-conflict layout (128-B concat rows,
// chunk ^ (row&7) involution on stage-source and ds_read).
// T5 setprio around each 24-MFMA cluster.
// A-frag A[m=lane&15][k=(lane>>4)*8+j]; C/D col=lane&15,row=(lane>>4)*4+reg.
// ---------------------------------------------------------------------------
__global__ __launch_bounds__(512, 2)
void gemm_key_fused(const ushort* __restrict__ embH, const ushort* __restrict__ embL,
                    const ushort* __restrict__ kwH,  const ushort* __restrict__ kwL,
                    const float* __restrict__ key_b, const float* __restrict__ hid,
                    const float* __restrict__ wkn,   const float* __restrict__ wqn,
                    float* __restrict__ k2_part, float* __restrict__ dot_part,
                    float* __restrict__ q2_part)
{
  constexpr int NT = 32;   // 1024 real K / 32 per tile
  __shared__ __align__(16) ushort sA[2 * 16384];  // [buf][256 rows][64 concat]
  __shared__ __align__(16) ushort sB[2 * 16384];

  const int tid  = threadIdx.x;
  const int lane = tid & 63;
  const int wave = tid >> 6;        // 0..7
  const int wm   = wave & 1;
  const int wn   = wave >> 1;       // 0..3
  const int l15  = lane & 15;
  const int cH   = (lane >> 4) ^ (lane & 7);   // swizzled H-chunk for ds_read
  const int row0 = blockIdx.y * 256;
  const int col0 = blockIdx.x * 256;

  // staging: round = 64 rows x 64 concat-cols (8 KB). thread covers row
  // tid>>3, LDS chunk tid&7 <- source chunk (tid&7)^(row&7); chunks 0-3 = H,
  // 4-7 = L, within-half elem offset (chunk&3)*8.
  const int sRow = tid >> 3;                       // 0..63
  const int schk = (tid & 7) ^ (sRow & 7);
  const ushort* aSel = (schk < 4) ? embH : embL;
  const ushort* bSel = (schk < 4) ? kwH  : kwL;
  const int sel8 = (schk & 3) * 8;
  const int wofs = wave * 512;                     // ushorts (64 lanes x 16B)

  auto stageA = [&](int rb, int u, int b) {
    const size_t co = (size_t)u * 32 + sel8;
    gld_lds16(aSel + (size_t)(row0 + rb + sRow) * Cc + co,
              sA + b * 16384 + (rb >> 6) * 4096 + wofs);
    gld_lds16(aSel + (size_t)(row0 + rb + 64 + sRow) * Cc + co,
              sA + b * 16384 + ((rb >> 6) + 1) * 4096 + wofs);
  };
  auto stageB = [&](int rb, int u, int b) {
    const size_t co = (size_t)u * 32 + sel8;
    gld_lds16(bSel + (size_t)(col0 + rb + sRow) * Cc + co,
              sB + b * 16384 + (rb >> 6) * 4096 + wofs);
    gld_lds16(bSel + (size_t)(col0 + rb + 64 + sRow) * Cc + co,
              sB + b * 16384 + ((rb >> 6) + 1) * 4096 + wofs);
  };

  f32x4_t acc[2][2][4][2] = {};   // [qm][qn][mi][ni]

#define PHASE(QM, QN, STAGE, DOVM)                                          \
  {                                                                         \
    bf16x8_t afH[4], afL[4], bgH[2], bgL[2];                                \
    _Pragma("unroll") for (int mi = 0; mi < 4; ++mi) {                      \
      const int r = (QM) * 128 + wm * 64 + mi * 16 + l15;                   \
      const ushort* pa = bufA + r * 64;                                     \
      afH[mi] = *(const bf16x8_t*)(pa + cH * 8);                            \
      afL[mi] = *(const bf16x8_t*)(pa + (cH ^ 4) * 8);                      \
    }                                                                       \
    _Pragma("unroll") for (int ni = 0; ni < 2; ++ni) {                      \
      const int r = (QN) * 128 + wn * 32 + ni * 16 + l15;                   \
      const ushort* pb = bufB + r * 64;                                     \
      bgH[ni] = *(const bf16x8_t*)(pb + cH * 8);                            \
      bgL[ni] = *(const bf16x8_t*)(pb + (cH ^ 4) * 8);                      \
    }                                                                       \
    STAGE;                                                                  \
    asm volatile("s_barrier" ::: "memory");                                 \
    asm volatile("s_waitcnt lgkmcnt(0)" ::: "memory");                      \
    __builtin_amdgcn_s_setprio(1);                                          \
    _Pragma("unroll") for (int mi = 0; mi < 4; ++mi)                        \
      _Pragma("unroll") for (int ni = 0; ni < 2; ++ni) {                    \
        acc[QM][QN][mi][ni] = __builtin_amdgcn_mfma_f32_16x16x32_bf16(      \
            afH[mi], bgH[ni], acc[QM][QN][mi][ni], 0, 0, 0);                \
        acc[QM][QN][mi][ni] = __builtin_amdgcn_mfma_f32_16x16x32_bf16(      \
            afH[mi], bgL[ni], acc[QM][QN][mi][ni], 0, 0, 0);                \
        acc[QM][QN][mi][ni] = __builtin_amdgcn_mfma_f32_16x16x32_bf16(      \
            afL[mi], bgH[ni], acc[QM][QN][mi][ni], 0, 0, 0);                \
      }                                                                     \
    __builtin_amdgcn_s_setprio(0);                                          \
    if (DOVM) { asm volatile("s_waitcnt vmcnt(4)" ::: "memory"); }          \
    asm volatile("s_barrier" ::: "memory");                                 \
  }

  // prologue: tile 0's 4 pairs in FIFO order, confirm first 2 pairs
  stageA(0, 0, 0); stageB(0, 0, 0); stageB(128, 0, 0); stageA(128, 0, 0);
  asm volatile("s_waitcnt vmcnt(4)" ::: "memory");
  asm volatile("s_barrier" ::: "memory");

  for (int u = 0; u < NT; ++u) {
    const int b = u & 1, nb = b ^ 1;
    const ushort* bufA = sA + b * 16384;
    const ushort* bufB = sB + b * 16384;
    const bool pf = (u + 1 < NT);
    PHASE(0, 0, if (pf) stageA(0, u + 1, nb),   1)
    PHASE(0, 1, if (pf) stageB(0, u + 1, nb),   1)
    PHASE(1, 0, if (pf) stageB(128, u + 1, nb), 0)
    PHASE(1, 1, if (pf) stageA(128, u + 1, nb), 1)
  }
#undef PHASE

  // ---- fused gate-reduction epilogue ----
  const int lrow = lane >> 4;
  const int lcol = lane & 15;
  const int g    = col0 >> 10;   // 256-col block lies within one group

#pragma unroll
  for (int qm = 0; qm < 2; ++qm) {
    float s2[4][4] = {}, su[4][4] = {}, sq[4][4] = {};
#pragma unroll
    for (int qn = 0; qn < 2; ++qn)
#pragma unroll
      for (int ni = 0; ni < 2; ++ni) {
        const int col = col0 + qn * 128 + wn * 32 + ni * 16 + lcol;
        const float kb = key_b[col];
        const float ww = wkn[col] * wqn[col];
#pragma unroll
        for (int mi = 0; mi < 4; ++mi) {
          const int rowb = row0 + qm * 128 + wm * 64 + mi * 16 + lrow * 4;
#pragma unroll
          for (int r = 0; r < 4; ++r) {
            const float q = hid[(size_t)(rowb + r) * GC + col];
            const float k = acc[qm][qn][mi][ni][r] + kb;
            s2[mi][r] += k * k;
            su[mi][r] += k * ww * q;
            sq[mi][r] += q * q;
          }
        }
      }
#pragma unroll
    for (int off = 1; off < 16; off <<= 1) {
#pragma unroll
      for (int mi = 0; mi < 4; ++mi)
#pragma unroll
        for (int r = 0; r < 4; ++r) {
          s2[mi][r] += __shfl_xor(s2[mi][r], off);
          su[mi][r] += __shfl_xor(su[mi][r], off);
          sq[mi][r] += __shfl_xor(sq[mi][r], off);
        }
    }
    if (lcol == 0) {
#pragma unroll
      for (int mi = 0; mi < 4; ++mi) {
        const int rowb = row0 + qm * 128 + wm * 64 + mi * 16 + lrow * 4;
#pragma unroll
        for (int r = 0; r < 4; ++r) {
          atomicAdd(&k2_part[(rowb + r) * Gg + g],  s2[mi][r]);
          atomicAdd(&dot_part[(rowb + r) * Gg + g], su[mi][r]);
          atomicAdd(&q2_part[(rowb + r) * Gg + g],  sq[mi][r]);
        }
      }
    }
  }
}

// ---------------------------------------------------------------------------
// GEMM2: vproj = embH @ vwB^T + val_b  (plain bf16, fp32 out).
// R5 structure: single 32 KiB buffer, syncthreads, st-8x64 swizzle, (256,4).
// ---------------------------------------------------------------------------
template <typename OutT>
__global__ __launch_bounds__(256, 4)
void gemm_bt(const ushort* __restrict__ A, const ushort* __restrict__ Bm,
             const float* __restrict__ bias, OutT* __restrict__ C,
             int M, int N, int K)
{
  __shared__ __align__(16) ushort sA[128 * 64];
  __shared__ __align__(16) ushort sB[128 * 64];

  const int tid  = threadIdx.x;
  const int lane = tid & 63;
  const int wave = tid >> 6;
  const int wm   = wave & 1;
  const int wn   = wave >> 1;
  const int row0 = blockIdx.y * 128;
  const int col0 = blockIdx.x * 128;

  const int srow = tid >> 3;
  const int scol = ((tid & 7) ^ (srow & 7)) * 8;
  ushort* aWB = sA + wave * 512;
  ushort* bWB = sB + wave * 512;

  f32x4_t acc[4][4] = {};

  for (int kt = 0; kt < K; kt += 64) {
#pragma unroll
    for (int p = 0; p < 4; ++p) {
      gld_lds16(A  + (size_t)(row0 + p * 32 + srow) * K + kt + scol,
                aWB + p * 2048);
      gld_lds16(Bm + (size_t)(col0 + p * 32 + srow) * K + kt + scol,
                bWB + p * 2048);
    }
    __syncthreads();

#pragma unroll
    for (int ks = 0; ks < 2; ++ks) {
      const int cb = ks * 4 + (lane >> 4);
      const int ce = ((cb ^ (lane & 7)) * 8);
      bf16x8_t af[4], bfr[4];
#pragma unroll
      for (int mi = 0; mi < 4; ++mi) {
        const int r = wm * 64 + mi * 16 + (lane & 15);
        af[mi] = *(const bf16x8_t*)(sA + r * 64 + ce);
      }
#pragma unroll
      for (int ni = 0; ni < 4; ++ni) {
        const int r = wn * 64 + ni * 16 + (lane & 15);
        bfr[ni] = *(const bf16x8_t*)(sB + r * 64 + ce);
      }
#pragma unroll
      for (int mi = 0; mi < 4; ++mi)
#pragma unroll
        for (int ni = 0; ni < 4; ++ni)
          acc[mi][ni] = __builtin_amdgcn_mfma_f32_16x16x32_bf16(
              af[mi], bfr[ni], acc[mi][ni], 0, 0, 0);
    }
    __syncthreads();
  }

  const int lrow = lane >> 4;
  const int lcol = lane & 15;
#pragma unroll
  for (int ni = 0; ni < 4; ++ni) {
    const int col = col0 + wn * 64 + ni * 16 + lcol;
    const float bv = bias[col];
#pragma unroll
    for (int mi = 0; mi < 4; ++mi) {
      const int rowb = row0 + wm * 64 + mi * 16 + lrow * 4;
#pragma unroll
      for (int r = 0; r < 4; ++r)
        store_val(&C[(size_t)(rowb + r) * N + col], acc[mi][ni][r] + bv);
    }
  }
}

// ---------------------------------------------------------------------------
// Finalize: per (b,t) compute mean(vproj^2); combine with atomic partials to
// produce gate[b,t,g] and snorm[b,t,g] = gate/rms_v.
// ---------------------------------------------------------------------------
__global__ __launch_bounds__(256)
void finalize_kernel(const float* __restrict__ vproj,
                     const float* __restrict__ k2_part,
                     const float* __restrict__ dot_part,
                     const float* __restrict__ q2_part,
                     float* __restrict__ gate_o, float* __restrict__ snorm_o)
{
  const int bt   = blockIdx.x;
  const int tid  = threadIdx.x;
  const int g    = tid >> 6;
  const int lane = tid & 63;

  const float4 v4 = ((const float4*)(vproj + (size_t)bt * Cc))[tid];
  float pv = v4.x * v4.x + v4.y * v4.y + v4.z * v4.z + v4.w * v4.w;
#pragma unroll
  for (int off = 32; off > 0; off >>= 1) pv += __shfl_xor(pv, off);
  __shared__ float wsum[4];
  if (lane == 0) wsum[g] = pv;
  __syncthreads();

  if (lane == 0) {
    const float mv = (wsum[0] + wsum[1] + wsum[2] + wsum[3]) * (1.0f / 1024.0f);
    const float sk = k2_part[bt * Gg + g];
    const float sd = dot_part[bt * Gg + g];
    const float sq = q2_part[bt * Gg + g];
    const float rk = sqrtf(sk * (1.0f / 1024.0f) + 1e-5f);
    const float rq = sqrtf(sq * (1.0f / 1024.0f) + 1e-5f);
    const float graw = sd / (rk * rq) * (1.0f / 32.0f);   // sqrt(C)=32
    const float sgn = (graw >= 0.f) ? 1.f : -1.f;
    const float gate = 1.f / (1.f + expf(-sgn * sqrtf(fmaxf(fabsf(graw), 1e-6f))));
    const float rv = sqrtf(gate * gate * mv + 1e-5f);
    gate_o[bt * Gg + g]  = gate;
    snorm_o[bt * Gg + g] = gate / rv;
  }
}

// ---------------------------------------------------------------------------
// Conv: lags {0,3,6,9} share t mod 3 -> 3 phase subsequences, lag-1 K=4 conv.
// Thread = (b,g,c,phase,chunk); 3 running normed values; 3-step halo.
// ---------------------------------------------------------------------------
static constexpr int CJ  = 128;
static constexpr int NCH = 11;   // ceil(ceil(4096/3)/128)

__global__ __launch_bounds__(256)
void conv_kernel(const float* __restrict__ vproj, const float* __restrict__ gate,
                 const float* __restrict__ snorm, const float* __restrict__ wnm,
                 const float* __restrict__ cw, float* __restrict__ out)
{
  int x = blockIdx.x;
  const int cb = x & 3;  x >>= 2;
  const int p  = x % 3;  x /= 3;
  const int ch = x % NCH; x /= NCH;
  const int g  = x & 3;  x >>= 2;
  const int b  = x;
  const int c  = cb * 256 + threadIdx.x;

  const float wn = wnm[g * Cc + c];
  const float4 w = ((const float4*)cw)[g * Cc + c];

  int t = p + 3 * (ch * CJ);
  if (t >= Tt) return;

  float n1 = 0.f, n2 = 0.f, n3 = 0.f;
#pragma unroll
  for (int h = 3; h >= 1; --h) {
    const int th = t - 3 * h;
    float nv = 0.f;
    if (th >= 0) {
      const int bt = b * Tt + th;
      nv = vproj[(size_t)bt * Cc + c] * snorm[bt * Gg + g] * wn;
    }
    n3 = n2; n2 = n1; n1 = nv;
  }

  for (int j = 0; j < CJ && t < Tt; ++j, t += 3) {
    const int bt = b * Tt + t;
    const float vp  = vproj[(size_t)bt * Cc + c];
    const float gt  = gate[bt * Gg + g];
    const float sn  = snorm[bt * Gg + g];
    const float cur = vp * sn * wn;
    const float a   = w.x * n3 + w.y * n2 + w.z * n1 + w.w * cur;
    const float si  = a / (1.f + __expf(-a));
    out[((size_t)bt * Gg + g) * Cc + c] = vp * gt + si;
    n3 = n2; n2 = n1; n1 = cur;
  }
}

// ---------------------------------------------------------------------------
extern "C" void kernel_launch(void* const* d_in, const int* in_sizes, int n_in,
                              void* d_out, int out_size, void* d_ws, size_t ws_size,
                              hipStream_t stream)
{
  const float* emb   = (const float*)d_in[0];
  const float* hid   = (const float*)d_in[1];
  const float* key_w = (const float*)d_in[2];
  const float* key_b = (const float*)d_in[3];
  const float* val_w = (const float*)d_in[4];
  const float* val_b = (const float*)d_in[5];
  const float* wkn   = (const float*)d_in[6];
  const float* wqn   = (const float*)d_in[7];
  const float* wnm   = (const float*)d_in[8];
  const float* cwt   = (const float*)d_in[9];
  float* out = (float*)d_out;

  // ws: embH 16.8M | embL 16.8M | kwH 8.4M | kwL 8.4M | vwB 2.1M |
  //     vproj 33.5M | k2/dot/q2/gate/snorm 5x128K   (~86.6 MB)
  char* ws = (char*)d_ws;
  ushort* embH  = (ushort*)ws;  ws += (size_t)Mm * Cc * 2;
  ushort* embL  = (ushort*)ws;  ws += (size_t)Mm * Cc * 2;
  ushort* kwH   = (ushort*)ws;  ws += (size_t)GC * Cc * 2;
  ushort* kwL   = (ushort*)ws;  ws += (size_t)GC * Cc * 2;
  ushort* vwB   = (ushort*)ws;  ws += (size_t)Cc * Cc * 2;
  float*  vproj = (float*)ws;   ws += (size_t)Mm * Cc * 4;
  float*  k2p   = (float*)ws;   ws += (size_t)Mm * Gg * 4;
  float*  dotp  = (float*)ws;   ws += (size_t)Mm * Gg * 4;
  float*  q2p   = (float*)ws;   ws += (size_t)Mm * Gg * 4;
  float*  gate  = (float*)ws;   ws += (size_t)Mm * Gg * 4;
  float*  snorm = (float*)ws;

  // zero the atomic partials (contiguous k2p|dotp|q2p)
  hipMemsetAsync(k2p, 0, (size_t)3 * Mm * Gg * 4, stream);

  dim3 blk(256);
  cvt_split<<<dim3((Mm * Cc / 4) / 256), blk, 0, stream>>>(emb,   embH, embL, Mm * Cc / 4);
  cvt_split<<<dim3((GC * Cc / 4) / 256), blk, 0, stream>>>(key_w, kwH,  kwL,  GC * Cc / 4);
  cvt_bf16 <<<dim3((Cc * Cc / 4) / 256), blk, 0, stream>>>(val_w, vwB,  Cc * Cc / 4);

  gemm_key_fused<<<dim3(GC / 256, Mm / 256), dim3(512), 0, stream>>>(
      embH, embL, kwH, kwL, key_b, hid, wkn, wqn, k2p, dotp, q2p);

  gemm_bt<float><<<dim3(Cc / 128, Mm / 128), blk, 0, stream>>>(
      embH, vwB, val_b, vproj, Mm, Cc, Cc);

  finalize_kernel<<<dim3(Mm), blk, 0, stream>>>(vproj, k2p, dotp, q2p, gate, snorm);

  const int nblocks = Bb * Gg * NCH * 3 * (Cc / 256);  // 1056
  conv_kernel<<<dim3(nblocks), blk, 0, stream>>>(vproj, gate, snorm, wnm, cwt, out);
}

// Round 8
// 584.871 us; speedup vs baseline: 1.0829x; 1.0065x over previous
//
#include <hip/hip_runtime.h>
#include <hip/hip_bf16.h>
#include <cstdint>
#include <cstddef>

using bf16 = __hip_bfloat16;

typedef __bf16 bf16x8_t __attribute__((ext_vector_type(8)));
typedef float  f32x4_t  __attribute__((ext_vector_type(4)));

static constexpr int Bb = 2;
static constexpr int Tt = 4096;
static constexpr int Gg = 4;
static constexpr int Cc = 1024;
static constexpr int Mm = Bb * Tt;   // 8192 rows (b*T+t)
static constexpr int GC = Gg * Cc;   // 4096

__device__ __forceinline__ float bfbits2f(unsigned u) {
  union { unsigned i; float f; } c; c.i = u << 16; return c.f;
}
__device__ __forceinline__ ushort f2bfbits(float v) {
  union { __hip_bfloat16 h; ushort u; } c; c.h = __float2bfloat16(v); return c.u;
}

__device__ __forceinline__ void store_val(bf16* p, float v)  { *p = __float2bfloat16(v); }
__device__ __forceinline__ void store_val(float* p, float v) { *p = v; }

// global -> LDS direct DMA, 16 B per lane. LDS dest must be the wave-uniform
// base (HW computes base + lane*16); global address is per-lane.
__device__ __forceinline__ void gld_lds16(const ushort* g, ushort* l) {
  __builtin_amdgcn_global_load_lds(
      (const __attribute__((address_space(1))) void*)g,
      (__attribute__((address_space(3))) void*)l, 16, 0, 0);
}

// ---------------------------------------------------------------------------
// fp32 -> bf16 (plain) and fp32 -> (hi, lo) split: hi = bf16(x),
// lo = bf16(x - hi). x-hi is exact in fp32 (Sterbenz), so hi+lo carries
// ~16 mantissa bits; bf16's fp32 exponent range means no subnormal hazards.
// ---------------------------------------------------------------------------
__global__ __launch_bounds__(256)
void cvt_bf16(const float* __restrict__ in, ushort* __restrict__ out, int n4)
{
  const int i = blockIdx.x * 256 + threadIdx.x;
  if (i >= n4) return;
  const float4 v = ((const float4*)in)[i];
  ushort4 o;
  o.x = f2bfbits(v.x); o.y = f2bfbits(v.y);
  o.z = f2bfbits(v.z); o.w = f2bfbits(v.w);
  ((ushort4*)out)[i] = o;
}

__global__ __launch_bounds__(256)
void cvt_split(const float* __restrict__ in, ushort* __restrict__ hi,
               ushort* __restrict__ lo, int n4)
{
  const int i = blockIdx.x * 256 + threadIdx.x;
  if (i >= n4) return;
  const float4 v = ((const float4*)in)[i];
  ushort4 h, l;
  h.x = f2bfbits(v.x); l.x = f2bfbits(v.x - bfbits2f(h.x));
  h.y = f2bfbits(v.y); l.y = f2bfbits(v.y - bfbits2f(h.y));
  h.z = f2bfbits(v.z); l.z = f2bfbits(v.z - bfbits2f(h.z));
  h.w = f2bfbits(v.w); l.w = f2bfbits(v.w - bfbits2f(h.w));
  ((ushort4*)hi)[i] = h;
  ((ushort4*)lo)[i] = l;
}

// ---------------------------------------------------------------------------
// GEMM1 (fused): split-bf16  k = embH@kwH^T + embH@kwL^T + embL@kwH^T + key_b,
// fp32 acc; 3 products fused per K-tile.
// R7 (resubmitted R8: prior bench was an infra double-failure, same signature
// as Round 0): barrier-LIGHT 256^2 tile. R6's per-phase barriers serialized
// LDS drain (1156 cyc) against MFMA (931 cyc) in 8-wave lockstep -> 2822
// cyc/phase, MfmaUtil pinned at 30%. Within a tile all reads hit buf b and
// staging writes buf nb, so NO intra-tile sync is needed: straight-line tile
// body {stage u+1 (8 gld_lds) | read B qn0+qn1 (8xb128, shared by 2
// quadrants each) | read A qm0 (8) | MFMA(0,0) | read A qm1 (8) | MFMA(0,1)
// (1,0) (1,1)} then ONE lgkmcnt(0)+vmcnt(0)+s_barrier per tile. hipcc's
// fine-grained lgkmcnt scheduling overlaps ds_reads under MFMA clusters.
// Tile reads 48->24 ds_read_b128 (B-frags read once, used twice).
// Hazards: stage(u+1)->nb disjoint from reads of b; stage(u+2)->b issued
// only after tile-u's barrier (preceded by lgkmcnt(0): all reads retired);
// reads of nb gated by vmcnt(0)+barrier (stage issued ~4000 cyc earlier).
// launch_bounds(512,1): LDS 128 KiB caps at 1 block/CU anyway; R6's (512,2)
// clamped VGPR to 128 for nothing. Frag live-range kept <=~210 VGPR by
// reading A(qm=1) after MFMA(0,0).
// T2 swizzle unchanged (R5-proven zero-conflict concat layout).
// A-frag A[m=lane&15][k=(lane>>4)*8+j]; C/D col=lane&15,row=(lane>>4)*4+reg.
// Product order per tile identical to R6 -> bit-identical numerics.
// ---------------------------------------------------------------------------
__global__ __launch_bounds__(512, 1)
void gemm_key_fused(const ushort* __restrict__ embH, const ushort* __restrict__ embL,
                    const ushort* __restrict__ kwH,  const ushort* __restrict__ kwL,
                    const float* __restrict__ key_b, const float* __restrict__ hid,
                    const float* __restrict__ wkn,   const float* __restrict__ wqn,
                    float* __restrict__ k2_part, float* __restrict__ dot_part,
                    float* __restrict__ q2_part)
{
  constexpr int NT = 32;   // 1024 real K / 32 per tile
  __shared__ __align__(16) ushort sA[2 * 16384];  // [buf][256 rows][64 concat]
  __shared__ __align__(16) ushort sB[2 * 16384];

  const int tid  = threadIdx.x;
  const int lane = tid & 63;
  const int wave = tid >> 6;        // 0..7
  const int wm   = wave & 1;
  const int wn   = wave >> 1;       // 0..3
  const int l15  = lane & 15;
  const int cHk  = (lane >> 4) ^ (lane & 7);   // swizzled H-chunk for ds_read
  const int row0 = blockIdx.y * 256;
  const int col0 = blockIdx.x * 256;

  // staging: round = 64 rows x 64 concat-cols (8 KB). thread covers row
  // tid>>3, LDS chunk tid&7 <- source chunk (tid&7)^(row&7); chunks 0-3 = H,
  // 4-7 = L, within-half elem offset (chunk&3)*8.
  const int sRow = tid >> 3;                       // 0..63
  const int schk = (tid & 7) ^ (sRow & 7);
  const ushort* aSel = (schk < 4) ? embH : embL;
  const ushort* bSel = (schk < 4) ? kwH  : kwL;
  const int sel8 = (schk & 3) * 8;
  const int wofs = wave * 512;                     // ushorts (64 lanes x 16B)

  auto stageA = [&](int rb, int u, int b) {
    const size_t co = (size_t)u * 32 + sel8;
    gld_lds16(aSel + (size_t)(row0 + rb + sRow) * Cc + co,
              sA + b * 16384 + (rb >> 6) * 4096 + wofs);
    gld_lds16(aSel + (size_t)(row0 + rb + 64 + sRow) * Cc + co,
              sA + b * 16384 + ((rb >> 6) + 1) * 4096 + wofs);
  };
  auto stageB = [&](int rb, int u, int b) {
    const size_t co = (size_t)u * 32 + sel8;
    gld_lds16(bSel + (size_t)(col0 + rb + sRow) * Cc + co,
              sB + b * 16384 + (rb >> 6) * 4096 + wofs);
    gld_lds16(bSel + (size_t)(col0 + rb + 64 + sRow) * Cc + co,
              sB + b * 16384 + ((rb >> 6) + 1) * 4096 + wofs);
  };

  f32x4_t acc[2][2][4][2] = {};   // [qm][qn][mi][ni]

#define MFMA3(QM, QN, AH, AL, BH, BL)                                       \
  _Pragma("unroll") for (int mi = 0; mi < 4; ++mi)                          \
    _Pragma("unroll") for (int ni = 0; ni < 2; ++ni) {                      \
      acc[QM][QN][mi][ni] = __builtin_amdgcn_mfma_f32_16x16x32_bf16(        \
          AH[mi], BH[ni], acc[QM][QN][mi][ni], 0, 0, 0);                    \
      acc[QM][QN][mi][ni] = __builtin_amdgcn_mfma_f32_16x16x32_bf16(        \
          AH[mi], BL[ni], acc[QM][QN][mi][ni], 0, 0, 0);                    \
      acc[QM][QN][mi][ni] = __builtin_amdgcn_mfma_f32_16x16x32_bf16(        \
          AL[mi], BH[ni], acc[QM][QN][mi][ni], 0, 0, 0);                    \
    }

  // prologue: stage tile 0 fully, wait, barrier
  stageA(0, 0, 0); stageB(0, 0, 0); stageB(128, 0, 0); stageA(128, 0, 0);
  asm volatile("s_waitcnt vmcnt(0)" ::: "memory");
  __builtin_amdgcn_s_barrier();

  for (int u = 0; u < NT; ++u) {
    const int b = u & 1, nb = b ^ 1;
    const ushort* bufA = sA + b * 16384;
    const ushort* bufB = sB + b * 16384;
    if (u + 1 < NT) {
      stageA(0, u + 1, nb);   stageB(0, u + 1, nb);
      stageB(128, u + 1, nb); stageA(128, u + 1, nb);
    }

    // B fragments for both qn quadrants (live across the whole tile)
    bf16x8_t b0H[2], b0L[2], b1H[2], b1L[2];
#pragma unroll
    for (int ni = 0; ni < 2; ++ni) {
      const ushort* p0 = bufB + (wn * 32 + ni * 16 + l15) * 64;
      const ushort* p1 = bufB + (128 + wn * 32 + ni * 16 + l15) * 64;
      b0H[ni] = *(const bf16x8_t*)(p0 + cHk * 8);
      b0L[ni] = *(const bf16x8_t*)(p0 + (cHk ^ 4) * 8);
      b1H[ni] = *(const bf16x8_t*)(p1 + cHk * 8);
      b1L[ni] = *(const bf16x8_t*)(p1 + (cHk ^ 4) * 8);
    }
    // A fragments qm=0
    bf16x8_t a0H[4], a0L[4];
#pragma unroll
    for (int mi = 0; mi < 4; ++mi) {
      const ushort* pa = bufA + (wm * 64 + mi * 16 + l15) * 64;
      a0H[mi] = *(const bf16x8_t*)(pa + cHk * 8);
      a0L[mi] = *(const bf16x8_t*)(pa + (cHk ^ 4) * 8);
    }
    __builtin_amdgcn_s_setprio(1);
    MFMA3(0, 0, a0H, a0L, b0H, b0L)
    __builtin_amdgcn_s_setprio(0);
    // A fragments qm=1 (drain under the remaining clusters)
    bf16x8_t a1H[4], a1L[4];
#pragma unroll
    for (int mi = 0; mi < 4; ++mi) {
      const ushort* pa = bufA + (128 + wm * 64 + mi * 16 + l15) * 64;
      a1H[mi] = *(const bf16x8_t*)(pa + cHk * 8);
      a1L[mi] = *(const bf16x8_t*)(pa + (cHk ^ 4) * 8);
    }
    __builtin_amdgcn_s_setprio(1);
    MFMA3(0, 1, a0H, a0L, b1H, b1L)
    MFMA3(1, 0, a1H, a1L, b0H, b0L)
    MFMA3(1, 1, a1H, a1L, b1H, b1L)
    __builtin_amdgcn_s_setprio(0);

    asm volatile("s_waitcnt lgkmcnt(0)" ::: "memory");  // all reads of buf b done
    asm volatile("s_waitcnt vmcnt(0)" ::: "memory");    // stage(u+1) landed
    __builtin_amdgcn_s_barrier();
  }
#undef MFMA3

  // ---- fused gate-reduction epilogue ----
  const int lrow = lane >> 4;
  const int lcol = lane & 15;
  const int g    = col0 >> 10;   // 256-col block lies within one group

#pragma unroll
  for (int qm = 0; qm < 2; ++qm) {
    float s2[4][4] = {}, su[4][4] = {}, sq[4][4] = {};
#pragma unroll
    for (int qn = 0; qn < 2; ++qn)
#pragma unroll
      for (int ni = 0; ni < 2; ++ni) {
        const int col = col0 + qn * 128 + wn * 32 + ni * 16 + lcol;
        const float kb = key_b[col];
        const float ww = wkn[col] * wqn[col];
#pragma unroll
        for (int mi = 0; mi < 4; ++mi) {
          const int rowb = row0 + qm * 128 + wm * 64 + mi * 16 + lrow * 4;
#pragma unroll
          for (int r = 0; r < 4; ++r) {
            const float q = hid[(size_t)(rowb + r) * GC + col];
            const float k = acc[qm][qn][mi][ni][r] + kb;
            s2[mi][r] += k * k;
            su[mi][r] += k * ww * q;
            sq[mi][r] += q * q;
          }
        }
      }
#pragma unroll
    for (int off = 1; off < 16; off <<= 1) {
#pragma unroll
      for (int mi = 0; mi < 4; ++mi)
#pragma unroll
        for (int r = 0; r < 4; ++r) {
          s2[mi][r] += __shfl_xor(s2[mi][r], off);
          su[mi][r] += __shfl_xor(su[mi][r], off);
          sq[mi][r] += __shfl_xor(sq[mi][r], off);
        }
    }
    if (lcol == 0) {
#pragma unroll
      for (int mi = 0; mi < 4; ++mi) {
        const int rowb = row0 + qm * 128 + wm * 64 + mi * 16 + lrow * 4;
#pragma unroll
        for (int r = 0; r < 4; ++r) {
          atomicAdd(&k2_part[(rowb + r) * Gg + g],  s2[mi][r]);
          atomicAdd(&dot_part[(rowb + r) * Gg + g], su[mi][r]);
          atomicAdd(&q2_part[(rowb + r) * Gg + g],  sq[mi][r]);
        }
      }
    }
  }
}

// ---------------------------------------------------------------------------
// GEMM2: vproj = embH @ vwB^T + val_b  (plain bf16, fp32 out).
// R5 structure: single 32 KiB buffer, syncthreads, st-8x64 swizzle, (256,4).
// ---------------------------------------------------------------------------
template <typename OutT>
__global__ __launch_bounds__(256, 4)
void gemm_bt(const ushort* __restrict__ A, const ushort* __restrict__ Bm,
             const float* __restrict__ bias, OutT* __restrict__ C,
             int M, int N, int K)
{
  __shared__ __align__(16) ushort sA[128 * 64];
  __shared__ __align__(16) ushort sB[128 * 64];

  const int tid  = threadIdx.x;
  const int lane = tid & 63;
  const int wave = tid >> 6;
  const int wm   = wave & 1;
  const int wn   = wave >> 1;
  const int row0 = blockIdx.y * 128;
  const int col0 = blockIdx.x * 128;

  const int srow = tid >> 3;
  const int scol = ((tid & 7) ^ (srow & 7)) * 8;
  ushort* aWB = sA + wave * 512;
  ushort* bWB = sB + wave * 512;

  f32x4_t acc[4][4] = {};

  for (int kt = 0; kt < K; kt += 64) {
#pragma unroll
    for (int p = 0; p < 4; ++p) {
      gld_lds16(A  + (size_t)(row0 + p * 32 + srow) * K + kt + scol,
                aWB + p * 2048);
      gld_lds16(Bm + (size_t)(col0 + p * 32 + srow) * K + kt + scol,
                bWB + p * 2048);
    }
    __syncthreads();

#pragma unroll
    for (int ks = 0; ks < 2; ++ks) {
      const int cb = ks * 4 + (lane >> 4);
      const int ce = ((cb ^ (lane & 7)) * 8);
      bf16x8_t af[4], bfr[4];
#pragma unroll
      for (int mi = 0; mi < 4; ++mi) {
        const int r = wm * 64 + mi * 16 + (lane & 15);
        af[mi] = *(const bf16x8_t*)(sA + r * 64 + ce);
      }
#pragma unroll
      for (int ni = 0; ni < 4; ++ni) {
        const int r = wn * 64 + ni * 16 + (lane & 15);
        bfr[ni] = *(const bf16x8_t*)(sB + r * 64 + ce);
      }
#pragma unroll
      for (int mi = 0; mi < 4; ++mi)
#pragma unroll
        for (int ni = 0; ni < 4; ++ni)
          acc[mi][ni] = __builtin_amdgcn_mfma_f32_16x16x32_bf16(
              af[mi], bfr[ni], acc[mi][ni], 0, 0, 0);
    }
    __syncthreads();
  }

  const int lrow = lane >> 4;
  const int lcol = lane & 15;
#pragma unroll
  for (int ni = 0; ni < 4; ++ni) {
    const int col = col0 + wn * 64 + ni * 16 + lcol;
    const float bv = bias[col];
#pragma unroll
    for (int mi = 0; mi < 4; ++mi) {
      const int rowb = row0 + wm * 64 + mi * 16 + lrow * 4;
#pragma unroll
      for (int r = 0; r < 4; ++r)
        store_val(&C[(size_t)(rowb + r) * N + col], acc[mi][ni][r] + bv);
    }
  }
}

// ---------------------------------------------------------------------------
// Finalize: per (b,t) compute mean(vproj^2); combine with atomic partials to
// produce gate[b,t,g] and snorm[b,t,g] = gate/rms_v.
// ---------------------------------------------------------------------------
__global__ __launch_bounds__(256)
void finalize_kernel(const float* __restrict__ vproj,
                     const float* __restrict__ k2_part,
                     const float* __restrict__ dot_part,
                     const float* __restrict__ q2_part,
                     float* __restrict__ gate_o, float* __restrict__ snorm_o)
{
  const int bt   = blockIdx.x;
  const int tid  = threadIdx.x;
  const int g    = tid >> 6;
  const int lane = tid & 63;

  const float4 v4 = ((const float4*)(vproj + (size_t)bt * Cc))[tid];
  float pv = v4.x * v4.x + v4.y * v4.y + v4.z * v4.z + v4.w * v4.w;
#pragma unroll
  for (int off = 32; off > 0; off >>= 1) pv += __shfl_xor(pv, off);
  __shared__ float wsum[4];
  if (lane == 0) wsum[g] = pv;
  __syncthreads();

  if (lane == 0) {
    const float mv = (wsum[0] + wsum[1] + wsum[2] + wsum[3]) * (1.0f / 1024.0f);
    const float sk = k2_part[bt * Gg + g];
    const float sd = dot_part[bt * Gg + g];
    const float sq = q2_part[bt * Gg + g];
    const float rk = sqrtf(sk * (1.0f / 1024.0f) + 1e-5f);
    const float rq = sqrtf(sq * (1.0f / 1024.0f) + 1e-5f);
    const float graw = sd / (rk * rq) * (1.0f / 32.0f);   // sqrt(C)=32
    const float sgn = (graw >= 0.f) ? 1.f : -1.f;
    const float gate = 1.f / (1.f + expf(-sgn * sqrtf(fmaxf(fabsf(graw), 1e-6f))));
    const float rv = sqrtf(gate * gate * mv + 1e-5f);
    gate_o[bt * Gg + g]  = gate;
    snorm_o[bt * Gg + g] = gate / rv;
  }
}

// ---------------------------------------------------------------------------
// Conv: lags {0,3,6,9} share t mod 3 -> 3 phase subsequences, lag-1 K=4 conv.
// Thread = (b,g,c,phase,chunk); 3 running normed values; 3-step halo.
// ---------------------------------------------------------------------------
static constexpr int CJ  = 128;
static constexpr int NCH = 11;   // ceil(ceil(4096/3)/128)

__global__ __launch_bounds__(256)
void conv_kernel(const float* __restrict__ vproj, const float* __restrict__ gate,
                 const float* __restrict__ snorm, const float* __restrict__ wnm,
                 const float* __restrict__ cw, float* __restrict__ out)
{
  int x = blockIdx.x;
  const int cb = x & 3;  x >>= 2;
  const int p  = x % 3;  x /= 3;
  const int ch = x % NCH; x /= NCH;
  const int g  = x & 3;  x >>= 2;
  const int b  = x;
  const int c  = cb * 256 + threadIdx.x;

  const float wn = wnm[g * Cc + c];
  const float4 w = ((const float4*)cw)[g * Cc + c];

  int t = p + 3 * (ch * CJ);
  if (t >= Tt) return;

  float n1 = 0.f, n2 = 0.f, n3 = 0.f;
#pragma unroll
  for (int h = 3; h >= 1; --h) {
    const int th = t - 3 * h;
    float nv = 0.f;
    if (th >= 0) {
      const int bt = b * Tt + th;
      nv = vproj[(size_t)bt * Cc + c] * snorm[bt * Gg + g] * wn;
    }
    n3 = n2; n2 = n1; n1 = nv;
  }

  for (int j = 0; j < CJ && t < Tt; ++j, t += 3) {
    const int bt = b * Tt + t;
    const float vp  = vproj[(size_t)bt * Cc + c];
    const float gt  = gate[bt * Gg + g];
    const float sn  = snorm[bt * Gg + g];
    const float cur = vp * sn * wn;
    const float a   = w.x * n3 + w.y * n2 + w.z * n1 + w.w * cur;
    const float si  = a / (1.f + __expf(-a));
    out[((size_t)bt * Gg + g) * Cc + c] = vp * gt + si;
    n3 = n2; n2 = n1; n1 = cur;
  }
}

// ---------------------------------------------------------------------------
extern "C" void kernel_launch(void* const* d_in, const int* in_sizes, int n_in,
                              void* d_out, int out_size, void* d_ws, size_t ws_size,
                              hipStream_t stream)
{
  const float* emb   = (const float*)d_in[0];
  const float* hid   = (const float*)d_in[1];
  const float* key_w = (const float*)d_in[2];
  const float* key_b = (const float*)d_in[3];
  const float* val_w = (const float*)d_in[4];
  const float* val_b = (const float*)d_in[5];
  const float* wkn   = (const float*)d_in[6];
  const float* wqn   = (const float*)d_in[7];
  const float* wnm   = (const float*)d_in[8];
  const float* cwt   = (const float*)d_in[9];
  float* out = (float*)d_out;

  // ws: embH 16.8M | embL 16.8M | kwH 8.4M | kwL 8.4M | vwB 2.1M |
  //     vproj 33.5M | k2/dot/q2/gate/snorm 5x128K   (~86.6 MB)
  char* ws = (char*)d_ws;
  ushort* embH  = (ushort*)ws;  ws += (size_t)Mm * Cc * 2;
  ushort* embL  = (ushort*)ws;  ws += (size_t)Mm * Cc * 2;
  ushort* kwH   = (ushort*)ws;  ws += (size_t)GC * Cc * 2;
  ushort* kwL   = (ushort*)ws;  ws += (size_t)GC * Cc * 2;
  ushort* vwB   = (ushort*)ws;  ws += (size_t)Cc * Cc * 2;
  float*  vproj = (float*)ws;   ws += (size_t)Mm * Cc * 4;
  float*  k2p   = (float*)ws;   ws += (size_t)Mm * Gg * 4;
  float*  dotp  = (float*)ws;   ws += (size_t)Mm * Gg * 4;
  float*  q2p   = (float*)ws;   ws += (size_t)Mm * Gg * 4;
  float*  gate  = (float*)ws;   ws += (size_t)Mm * Gg * 4;
  float*  snorm = (float*)ws;

  // zero the atomic partials (contiguous k2p|dotp|q2p)
  hipMemsetAsync(k2p, 0, (size_t)3 * Mm * Gg * 4, stream);

  dim3 blk(256);
  cvt_split<<<dim3((Mm * Cc / 4) / 256), blk, 0, stream>>>(emb,   embH, embL, Mm * Cc / 4);
  cvt_split<<<dim3((GC * Cc / 4) / 256), blk, 0, stream>>>(key_w, kwH,  kwL,  GC * Cc / 4);
  cvt_bf16 <<<dim3((Cc * Cc / 4) / 256), blk, 0, stream>>>(val_w, vwB,  Cc * Cc / 4);

  gemm_key_fused<<<dim3(GC / 256, Mm / 256), dim3(512), 0, stream>>>(
      embH, embL, kwH, kwL, key_b, hid, wkn, wqn, k2p, dotp, q2p);

  gemm_bt<float><<<dim3(Cc / 128, Mm / 128), blk, 0, stream>>>(
      embH, vwB, val_b, vproj, Mm, Cc, Cc);

  finalize_kernel<<<dim3(Mm), blk, 0, stream>>>(vproj, k2p, dotp, q2p, gate, snorm);

  const int nblocks = Bb * Gg * NCH * 3 * (Cc / 256);  // 1056
  conv_kernel<<<dim3(nblocks), blk, 0, stream>>>(vproj, gate, snorm, wnm, cwt, out);
}

// Round 9
// 580.057 us; speedup vs baseline: 1.0919x; 1.0083x over previous
//
#include <hip/hip_runtime.h>
#include <hip/hip_bf16.h>
#include <cstdint>
#include <cstddef>

using bf16 = __hip_bfloat16;

typedef __bf16 bf16x8_t __attribute__((ext_vector_type(8)));
typedef float  f32x4_t  __attribute__((ext_vector_type(4)));

static constexpr int Bb = 2;
static constexpr int Tt = 4096;
static constexpr int Gg = 4;
static constexpr int Cc = 1024;
static constexpr int Mm = Bb * Tt;   // 8192 rows (b*T+t)
static constexpr int GC = Gg * Cc;   // 4096

__device__ __forceinline__ float bfbits2f(unsigned u) {
  union { unsigned i; float f; } c; c.i = u << 16; return c.f;
}
__device__ __forceinline__ ushort f2bfbits(float v) {
  union { __hip_bfloat16 h; ushort u; } c; c.h = __float2bfloat16(v); return c.u;
}

// global -> LDS direct DMA, 16 B per lane. LDS dest must be the wave-uniform
// base (HW computes base + lane*16); global address is per-lane.
__device__ __forceinline__ void gld_lds16(const ushort* g, ushort* l) {
  __builtin_amdgcn_global_load_lds(
      (const __attribute__((address_space(1))) void*)g,
      (__attribute__((address_space(3))) void*)l, 16, 0, 0);
}

// ---------------------------------------------------------------------------
// R9: ONE conversion dispatch. Block ranges:
//   [0, 8192)        : emb fp32 -> (embH, embL) hi/lo split
//   [8192, 12288)    : key_w -> (kwH, kwL)
//   [12288, 13312)   : val_w -> vwB (plain bf16)
//   [13312, 13416)   : zero the 416 KB partials block (k2p|dotp|q2p|v2p)
// Replaces 3 cvt kernels + hipMemsetAsync (dispatch count 9 -> 4 overall).
// Split: hi = bf16(x), lo = bf16(x - hi); x-hi exact in fp32 (Sterbenz).
// ---------------------------------------------------------------------------
__global__ __launch_bounds__(256)
void cvt_all(const float* __restrict__ emb, const float* __restrict__ key_w,
             const float* __restrict__ val_w,
             ushort* __restrict__ embH, ushort* __restrict__ embL,
             ushort* __restrict__ kwH,  ushort* __restrict__ kwL,
             ushort* __restrict__ vwB,  float* __restrict__ zbase)
{
  const int bid = blockIdx.x;
  const int tid = threadIdx.x;
  if (bid < 12288) {
    const bool isE = bid < 8192;
    const int  i   = (isE ? bid : bid - 8192) * 256 + tid;
    const float4 v = ((const float4*)(isE ? emb : key_w))[i];
    ushort4 h, l;
    h.x = f2bfbits(v.x); l.x = f2bfbits(v.x - bfbits2f(h.x));
    h.y = f2bfbits(v.y); l.y = f2bfbits(v.y - bfbits2f(h.y));
    h.z = f2bfbits(v.z); l.z = f2bfbits(v.z - bfbits2f(h.z));
    h.w = f2bfbits(v.w); l.w = f2bfbits(v.w - bfbits2f(h.w));
    ((ushort4*)(isE ? embH : kwH))[i] = h;
    ((ushort4*)(isE ? embL : kwL))[i] = l;
  } else if (bid < 13312) {
    const int i = (bid - 12288) * 256 + tid;
    const float4 v = ((const float4*)val_w)[i];
    ushort4 o;
    o.x = f2bfbits(v.x); o.y = f2bfbits(v.y);
    o.z = f2bfbits(v.z); o.w = f2bfbits(v.w);
    ((ushort4*)vwB)[i] = o;
  } else {
    const int i = (bid - 13312) * 256 + tid;   // 26624 float4s = 416 KB
    ((float4*)zbase)[i] = make_float4(0.f, 0.f, 0.f, 0.f);
  }
}

// ---------------------------------------------------------------------------
// GEMM1 (fused): split-bf16  k = embH@kwH^T + embH@kwL^T + embL@kwH^T + key_b,
// fp32 acc; 3 products fused per K-tile. R8 structure UNCHANGED (best
// measured 289 us): barrier-light 256^2 tile, straight-line body, one
// lgkmcnt(0)+vmcnt(0)+s_barrier per tile, T2 concat swizzle, launch(512,1).
// A-frag A[m=lane&15][k=(lane>>4)*8+j]; C/D col=lane&15,row=(lane>>4)*4+reg.
// ---------------------------------------------------------------------------
__global__ __launch_bounds__(512, 1)
void gemm_key_fused(const ushort* __restrict__ embH, const ushort* __restrict__ embL,
                    const ushort* __restrict__ kwH,  const ushort* __restrict__ kwL,
                    const float* __restrict__ key_b, const float* __restrict__ hid,
                    const float* __restrict__ wkn,   const float* __restrict__ wqn,
                    float* __restrict__ k2_part, float* __restrict__ dot_part,
                    float* __restrict__ q2_part)
{
  constexpr int NT = 32;   // 1024 real K / 32 per tile
  __shared__ __align__(16) ushort sA[2 * 16384];  // [buf][256 rows][64 concat]
  __shared__ __align__(16) ushort sB[2 * 16384];

  const int tid  = threadIdx.x;
  const int lane = tid & 63;
  const int wave = tid >> 6;        // 0..7
  const int wm   = wave & 1;
  const int wn   = wave >> 1;       // 0..3
  const int l15  = lane & 15;
  const int cHk  = (lane >> 4) ^ (lane & 7);   // swizzled H-chunk for ds_read
  const int row0 = blockIdx.y * 256;
  const int col0 = blockIdx.x * 256;

  const int sRow = tid >> 3;                       // 0..63
  const int schk = (tid & 7) ^ (sRow & 7);
  const ushort* aSel = (schk < 4) ? embH : embL;
  const ushort* bSel = (schk < 4) ? kwH  : kwL;
  const int sel8 = (schk & 3) * 8;
  const int wofs = wave * 512;                     // ushorts (64 lanes x 16B)

  auto stageA = [&](int rb, int u, int b) {
    const size_t co = (size_t)u * 32 + sel8;
    gld_lds16(aSel + (size_t)(row0 + rb + sRow) * Cc + co,
              sA + b * 16384 + (rb >> 6) * 4096 + wofs);
    gld_lds16(aSel + (size_t)(row0 + rb + 64 + sRow) * Cc + co,
              sA + b * 16384 + ((rb >> 6) + 1) * 4096 + wofs);
  };
  auto stageB = [&](int rb, int u, int b) {
    const size_t co = (size_t)u * 32 + sel8;
    gld_lds16(bSel + (size_t)(col0 + rb + sRow) * Cc + co,
              sB + b * 16384 + (rb >> 6) * 4096 + wofs);
    gld_lds16(bSel + (size_t)(col0 + rb + 64 + sRow) * Cc + co,
              sB + b * 16384 + ((rb >> 6) + 1) * 4096 + wofs);
  };

  f32x4_t acc[2][2][4][2] = {};   // [qm][qn][mi][ni]

#define MFMA3(QM, QN, AH, AL, BH, BL)                                       \
  _Pragma("unroll") for (int mi = 0; mi < 4; ++mi)                          \
    _Pragma("unroll") for (int ni = 0; ni < 2; ++ni) {                      \
      acc[QM][QN][mi][ni] = __builtin_amdgcn_mfma_f32_16x16x32_bf16(        \
          AH[mi], BH[ni], acc[QM][QN][mi][ni], 0, 0, 0);                    \
      acc[QM][QN][mi][ni] = __builtin_amdgcn_mfma_f32_16x16x32_bf16(        \
          AH[mi], BL[ni], acc[QM][QN][mi][ni], 0, 0, 0);                    \
      acc[QM][QN][mi][ni] = __builtin_amdgcn_mfma_f32_16x16x32_bf16(        \
          AL[mi], BH[ni], acc[QM][QN][mi][ni], 0, 0, 0);                    \
    }

  // prologue: stage tile 0 fully, wait, barrier
  stageA(0, 0, 0); stageB(0, 0, 0); stageB(128, 0, 0); stageA(128, 0, 0);
  asm volatile("s_waitcnt vmcnt(0)" ::: "memory");
  __builtin_amdgcn_s_barrier();

  for (int u = 0; u < NT; ++u) {
    const int b = u & 1, nb = b ^ 1;
    const ushort* bufA = sA + b * 16384;
    const ushort* bufB = sB + b * 16384;
    if (u + 1 < NT) {
      stageA(0, u + 1, nb);   stageB(0, u + 1, nb);
      stageB(128, u + 1, nb); stageA(128, u + 1, nb);
    }

    // B fragments for both qn quadrants (live across the whole tile)
    bf16x8_t b0H[2], b0L[2], b1H[2], b1L[2];
#pragma unroll
    for (int ni = 0; ni < 2; ++ni) {
      const ushort* p0 = bufB + (wn * 32 + ni * 16 + l15) * 64;
      const ushort* p1 = bufB + (128 + wn * 32 + ni * 16 + l15) * 64;
      b0H[ni] = *(const bf16x8_t*)(p0 + cHk * 8);
      b0L[ni] = *(const bf16x8_t*)(p0 + (cHk ^ 4) * 8);
      b1H[ni] = *(const bf16x8_t*)(p1 + cHk * 8);
      b1L[ni] = *(const bf16x8_t*)(p1 + (cHk ^ 4) * 8);
    }
    // A fragments qm=0
    bf16x8_t a0H[4], a0L[4];
#pragma unroll
    for (int mi = 0; mi < 4; ++mi) {
      const ushort* pa = bufA + (wm * 64 + mi * 16 + l15) * 64;
      a0H[mi] = *(const bf16x8_t*)(pa + cHk * 8);
      a0L[mi] = *(const bf16x8_t*)(pa + (cHk ^ 4) * 8);
    }
    __builtin_amdgcn_s_setprio(1);
    MFMA3(0, 0, a0H, a0L, b0H, b0L)
    __builtin_amdgcn_s_setprio(0);
    // A fragments qm=1 (drain under the remaining clusters)
    bf16x8_t a1H[4], a1L[4];
#pragma unroll
    for (int mi = 0; mi < 4; ++mi) {
      const ushort* pa = bufA + (128 + wm * 64 + mi * 16 + l15) * 64;
      a1H[mi] = *(const bf16x8_t*)(pa + cHk * 8);
      a1L[mi] = *(const bf16x8_t*)(pa + (cHk ^ 4) * 8);
    }
    __builtin_amdgcn_s_setprio(1);
    MFMA3(0, 1, a0H, a0L, b1H, b1L)
    MFMA3(1, 0, a1H, a1L, b0H, b0L)
    MFMA3(1, 1, a1H, a1L, b1H, b1L)
    __builtin_amdgcn_s_setprio(0);

    asm volatile("s_waitcnt lgkmcnt(0)" ::: "memory");  // all reads of buf b done
    asm volatile("s_waitcnt vmcnt(0)" ::: "memory");    // stage(u+1) landed
    __builtin_amdgcn_s_barrier();
  }
#undef MFMA3

  // ---- fused gate-reduction epilogue ----
  const int lrow = lane >> 4;
  const int lcol = lane & 15;
  const int g    = col0 >> 10;   // 256-col block lies within one group

#pragma unroll
  for (int qm = 0; qm < 2; ++qm) {
    float s2[4][4] = {}, su[4][4] = {}, sq[4][4] = {};
#pragma unroll
    for (int qn = 0; qn < 2; ++qn)
#pragma unroll
      for (int ni = 0; ni < 2; ++ni) {
        const int col = col0 + qn * 128 + wn * 32 + ni * 16 + lcol;
        const float kb = key_b[col];
        const float ww = wkn[col] * wqn[col];
#pragma unroll
        for (int mi = 0; mi < 4; ++mi) {
          const int rowb = row0 + qm * 128 + wm * 64 + mi * 16 + lrow * 4;
#pragma unroll
          for (int r = 0; r < 4; ++r) {
            const float q = hid[(size_t)(rowb + r) * GC + col];
            const float k = acc[qm][qn][mi][ni][r] + kb;
            s2[mi][r] += k * k;
            su[mi][r] += k * ww * q;
            sq[mi][r] += q * q;
          }
        }
      }
#pragma unroll
    for (int off = 1; off < 16; off <<= 1) {
#pragma unroll
      for (int mi = 0; mi < 4; ++mi)
#pragma unroll
        for (int r = 0; r < 4; ++r) {
          s2[mi][r] += __shfl_xor(s2[mi][r], off);
          su[mi][r] += __shfl_xor(su[mi][r], off);
          sq[mi][r] += __shfl_xor(sq[mi][r], off);
        }
    }
    if (lcol == 0) {
#pragma unroll
      for (int mi = 0; mi < 4; ++mi) {
        const int rowb = row0 + qm * 128 + wm * 64 + mi * 16 + lrow * 4;
#pragma unroll
        for (int r = 0; r < 4; ++r) {
          atomicAdd(&k2_part[(rowb + r) * Gg + g],  s2[mi][r]);
          atomicAdd(&dot_part[(rowb + r) * Gg + g], su[mi][r]);
          atomicAdd(&q2_part[(rowb + r) * Gg + g],  sq[mi][r]);
        }
      }
    }
  }
}

// ---------------------------------------------------------------------------
// GEMM2: vproj = embH @ vwB^T + val_b  (fp32 out). R5 structure.
// R9 addition: epilogue also reduces sum(vproj^2) per row (shuffle over the
// 16 lcol lanes + atomicAdd per row per wave) into v2_part -- removes the
// separate finalize pass over vproj (33.5 MB re-read).
// ---------------------------------------------------------------------------
__global__ __launch_bounds__(256, 4)
void gemm_bt(const ushort* __restrict__ A, const ushort* __restrict__ Bm,
             const float* __restrict__ bias, float* __restrict__ C,
             float* __restrict__ v2_part, int M, int N, int K)
{
  __shared__ __align__(16) ushort sA[128 * 64];
  __shared__ __align__(16) ushort sB[128 * 64];

  const int tid  = threadIdx.x;
  const int lane = tid & 63;
  const int wave = tid >> 6;
  const int wm   = wave & 1;
  const int wn   = wave >> 1;
  const int row0 = blockIdx.y * 128;
  const int col0 = blockIdx.x * 128;

  const int srow = tid >> 3;
  const int scol = ((tid & 7) ^ (srow & 7)) * 8;
  ushort* aWB = sA + wave * 512;
  ushort* bWB = sB + wave * 512;

  f32x4_t acc[4][4] = {};

  for (int kt = 0; kt < K; kt += 64) {
#pragma unroll
    for (int p = 0; p < 4; ++p) {
      gld_lds16(A  + (size_t)(row0 + p * 32 + srow) * K + kt + scol,
                aWB + p * 2048);
      gld_lds16(Bm + (size_t)(col0 + p * 32 + srow) * K + kt + scol,
                bWB + p * 2048);
    }
    __syncthreads();

#pragma unroll
    for (int ks = 0; ks < 2; ++ks) {
      const int cb = ks * 4 + (lane >> 4);
      const int ce = ((cb ^ (lane & 7)) * 8);
      bf16x8_t af[4], bfr[4];
#pragma unroll
      for (int mi = 0; mi < 4; ++mi) {
        const int r = wm * 64 + mi * 16 + (lane & 15);
        af[mi] = *(const bf16x8_t*)(sA + r * 64 + ce);
      }
#pragma unroll
      for (int ni = 0; ni < 4; ++ni) {
        const int r = wn * 64 + ni * 16 + (lane & 15);
        bfr[ni] = *(const bf16x8_t*)(sB + r * 64 + ce);
      }
#pragma unroll
      for (int mi = 0; mi < 4; ++mi)
#pragma unroll
        for (int ni = 0; ni < 4; ++ni)
          acc[mi][ni] = __builtin_amdgcn_mfma_f32_16x16x32_bf16(
              af[mi], bfr[ni], acc[mi][ni], 0, 0, 0);
    }
    __syncthreads();
  }

  const int lrow = lane >> 4;
  const int lcol = lane & 15;
  float sv[4][4] = {};
#pragma unroll
  for (int ni = 0; ni < 4; ++ni) {
    const int col = col0 + wn * 64 + ni * 16 + lcol;
    const float bv = bias[col];
#pragma unroll
    for (int mi = 0; mi < 4; ++mi) {
      const int rowb = row0 + wm * 64 + mi * 16 + lrow * 4;
#pragma unroll
      for (int r = 0; r < 4; ++r) {
        const float v = acc[mi][ni][r] + bv;
        C[(size_t)(rowb + r) * N + col] = v;
        sv[mi][r] += v * v;
      }
    }
  }
#pragma unroll
  for (int off = 1; off < 16; off <<= 1)
#pragma unroll
    for (int mi = 0; mi < 4; ++mi)
#pragma unroll
      for (int r = 0; r < 4; ++r)
        sv[mi][r] += __shfl_xor(sv[mi][r], off);
  if (lcol == 0) {
#pragma unroll
    for (int mi = 0; mi < 4; ++mi) {
      const int rowb = row0 + wm * 64 + mi * 16 + lrow * 4;
#pragma unroll
      for (int r = 0; r < 4; ++r)
        atomicAdd(&v2_part[rowb + r], sv[mi][r]);
    }
  }
}

// ---------------------------------------------------------------------------
// Conv v2 (R9): float4-coalesced + inline gate/snorm (replaces finalize).
// Thread owns 4 consecutive c -> block of 256 threads reads/writes 4 KB
// contiguous per (bt,g) step (was 1 KB read / 256 B-per-wave write at 16 KB
// stride). gate/snorm computed per-t from the atomic partials (thread-
// uniform: 4 L2 loads + ~20 VALU) -- same formulas as the old finalize.
// Lags {0,3,6,9} share t mod 3 -> phase subsequences, lag-1 K=4 conv with
// 3-deep register history; 3-step halo recomputes snorm only.
// ---------------------------------------------------------------------------
static constexpr int CJ2  = 32;
static constexpr int NCH2 = 43;   // ceil(ceil(4096/3)/32)

__device__ __forceinline__ float2 gate_snorm(
    const float* __restrict__ k2p, const float* __restrict__ dotp,
    const float* __restrict__ q2p, const float* __restrict__ v2p,
    int bt, int g)
{
  const float sk = k2p[bt * Gg + g];
  const float sd = dotp[bt * Gg + g];
  const float sq = q2p[bt * Gg + g];
  const float mv = v2p[bt] * (1.0f / 1024.0f);
  const float rk = sqrtf(sk * (1.0f / 1024.0f) + 1e-5f);
  const float rq = sqrtf(sq * (1.0f / 1024.0f) + 1e-5f);
  const float graw = sd / (rk * rq) * (1.0f / 32.0f);   // sqrt(C)=32
  const float sgn = (graw >= 0.f) ? 1.f : -1.f;
  const float gate = 1.f / (1.f + expf(-sgn * sqrtf(fmaxf(fabsf(graw), 1e-6f))));
  const float rv = sqrtf(gate * gate * mv + 1e-5f);
  return make_float2(gate, gate / rv);
}

__global__ __launch_bounds__(256)
void conv_kernel(const float* __restrict__ vproj,
                 const float* __restrict__ k2p, const float* __restrict__ dotp,
                 const float* __restrict__ q2p, const float* __restrict__ v2p,
                 const float* __restrict__ wnm, const float* __restrict__ cw,
                 float* __restrict__ out)
{
  int x = blockIdx.x;
  const int p  = x % 3;    x /= 3;
  const int ch = x % NCH2; x /= NCH2;
  const int g  = x & 3;    x >>= 2;
  const int b  = x;
  const int c4 = threadIdx.x;          // float4 index: cols 4*c4 .. 4*c4+3

  const float4 wn4 = ((const float4*)wnm)[g * 256 + c4];
  const int cbase = g * Cc + 4 * c4;
  const float4 w0 = ((const float4*)cw)[cbase + 0];
  const float4 w1 = ((const float4*)cw)[cbase + 1];
  const float4 w2 = ((const float4*)cw)[cbase + 2];
  const float4 w3 = ((const float4*)cw)[cbase + 3];

  int t = p + 3 * (ch * CJ2);
  if (t >= Tt) return;

  float4 n1 = make_float4(0,0,0,0), n2 = n1, n3 = n1;
#pragma unroll
  for (int h = 3; h >= 1; --h) {
    const int th = t - 3 * h;
    float4 nv = make_float4(0,0,0,0);
    if (th >= 0) {
      const int bt = b * Tt + th;
      const float2 gs = gate_snorm(k2p, dotp, q2p, v2p, bt, g);
      const float4 vp = ((const float4*)vproj)[(size_t)bt * 256 + c4];
      const float s = gs.y;
      nv = make_float4(vp.x * s * wn4.x, vp.y * s * wn4.y,
                       vp.z * s * wn4.z, vp.w * s * wn4.w);
    }
    n3 = n2; n2 = n1; n1 = nv;
  }

  for (int j = 0; j < CJ2 && t < Tt; ++j, t += 3) {
    const int bt = b * Tt + t;
    const float2 gs = gate_snorm(k2p, dotp, q2p, v2p, bt, g);
    const float4 vp = ((const float4*)vproj)[(size_t)bt * 256 + c4];
    const float sn = gs.y, gt = gs.x;
    float4 cur = make_float4(vp.x * sn * wn4.x, vp.y * sn * wn4.y,
                             vp.z * sn * wn4.z, vp.w * sn * wn4.w);
    float4 a;
    a.x = w0.x * n3.x + w0.y * n2.x + w0.z * n1.x + w0.w * cur.x;
    a.y = w1.x * n3.y + w1.y * n2.y + w1.z * n1.y + w1.w * cur.y;
    a.z = w2.x * n3.z + w2.y * n2.z + w2.z * n1.z + w2.w * cur.z;
    a.w = w3.x * n3.w + w3.y * n2.w + w3.z * n1.w + w3.w * cur.w;
    float4 o;
    o.x = vp.x * gt + a.x / (1.f + __expf(-a.x));
    o.y = vp.y * gt + a.y / (1.f + __expf(-a.y));
    o.z = vp.z * gt + a.z / (1.f + __expf(-a.z));
    o.w = vp.w * gt + a.w / (1.f + __expf(-a.w));
    ((float4*)out)[((size_t)bt * Gg + g) * 256 + c4] = o;
    n3 = n2; n2 = n1; n1 = cur;
  }
}

// ---------------------------------------------------------------------------
extern "C" void kernel_launch(void* const* d_in, const int* in_sizes, int n_in,
                              void* d_out, int out_size, void* d_ws, size_t ws_size,
                              hipStream_t stream)
{
  const float* emb   = (const float*)d_in[0];
  const float* hid   = (const float*)d_in[1];
  const float* key_w = (const float*)d_in[2];
  const float* key_b = (const float*)d_in[3];
  const float* val_w = (const float*)d_in[4];
  const float* val_b = (const float*)d_in[5];
  const float* wkn   = (const float*)d_in[6];
  const float* wqn   = (const float*)d_in[7];
  const float* wnm   = (const float*)d_in[8];
  const float* cwt   = (const float*)d_in[9];
  float* out = (float*)d_out;

  // ws: embH 16.8M | embL 16.8M | kwH 8.4M | kwL 8.4M | vwB 2.1M |
  //     vproj 33.5M | k2p/dotp/q2p 3x128K | v2p 32K   (~86.5 MB)
  char* ws = (char*)d_ws;
  ushort* embH  = (ushort*)ws;  ws += (size_t)Mm * Cc * 2;
  ushort* embL  = (ushort*)ws;  ws += (size_t)Mm * Cc * 2;
  ushort* kwH   = (ushort*)ws;  ws += (size_t)GC * Cc * 2;
  ushort* kwL   = (ushort*)ws;  ws += (size_t)GC * Cc * 2;
  ushort* vwB   = (ushort*)ws;  ws += (size_t)Cc * Cc * 2;
  float*  vproj = (float*)ws;   ws += (size_t)Mm * Cc * 4;
  float*  k2p   = (float*)ws;   ws += (size_t)Mm * Gg * 4;
  float*  dotp  = (float*)ws;   ws += (size_t)Mm * Gg * 4;
  float*  q2p   = (float*)ws;   ws += (size_t)Mm * Gg * 4;
  float*  v2p   = (float*)ws;

  // 4 dispatches total (was 9): cvt_all(+zero) -> gemm1 -> gemm_bt(+v2p) -> conv
  cvt_all<<<dim3(13416), dim3(256), 0, stream>>>(
      emb, key_w, val_w, embH, embL, kwH, kwL, vwB, k2p);

  gemm_key_fused<<<dim3(GC / 256, Mm / 256), dim3(512), 0, stream>>>(
      embH, embL, kwH, kwL, key_b, hid, wkn, wqn, k2p, dotp, q2p);

  gemm_bt<<<dim3(Cc / 128, Mm / 128), dim3(256), 0, stream>>>(
      embH, vwB, val_b, vproj, v2p, Mm, Cc, Cc);

  const int nblocks = Bb * Gg * NCH2 * 3;  // 1032
  conv_kernel<<<dim3(nblocks), dim3(256), 0, stream>>>(
      vproj, k2p, dotp, q2p, v2p, wnm, cwt, out);
}